// Round 10
// baseline (1588.683 us; speedup 1.0000x reference)
//
#include <hip/hip_runtime.h>
#include <math.h>

typedef unsigned short u16;
typedef unsigned int   u32;

#define B_ 2
#define S_ 2048
#define F_ 512
#define I_ 1024
#define E_ 8
#define KW_ 7
#define D_ 2
#define CLASSES_ 8192
#define T_ (B_*S_)
#define SP_ (S_+6)
#define NSLOT_ 9216
#define GMAX_ 72

typedef __bf16 bf16x8 __attribute__((ext_vector_type(8)));
typedef float  f32x4  __attribute__((ext_vector_type(4)));

__device__ __forceinline__ u16 f2b(float f) {
    u32 x = __float_as_uint(f);
    return (u16)((x + 0x7fffu + ((x >> 16) & 1u)) >> 16);
}
__device__ __forceinline__ void fsplit(float v, u16& h, u16& l) {
    u16 hh = f2b(v);
    float hv = __uint_as_float(((u32)hh) << 16);
    h = hh;
    l = f2b(v - hv);
}

template<int N> __device__ __forceinline__ void waitvm() {
    asm volatile("s_waitcnt vmcnt(%0)" :: "n"(N) : "memory");
}

#define GLDS16(g, l) __builtin_amdgcn_global_load_lds( \
    (const __attribute__((address_space(1))) u32*)(g), \
    (__attribute__((address_space(3))) u32*)(l), 16, 0, 0)

// ---------------- misc small kernels ----------------
__global__ void embed_k(const int* __restrict__ inp, const float* __restrict__ emb,
                        float* __restrict__ X0, float* __restrict__ X1)
{
    int t = blockIdx.x;
    int r = inp[t];
    const float* e = emb + (size_t)r * (2*F_);
    for (int c = threadIdx.x; c < F_; c += 256) {
        X0[(size_t)t*F_ + c] = e[c];
        X1[(size_t)t*F_ + c] = e[F_ + c];
    }
}

// one-time reset (covers 0xAA poison); afterwards sched_k maintains invariants
__global__ void initslot_k(int* __restrict__ stok, int* __restrict__ cnt)
{
    int i = blockIdx.x*256 + threadIdx.x;
    if (i < NSLOT_) stok[i] = -1;
    if (i < E_) cnt[i] = 0;
}

// ---- fused gate1 + X1 hi/lo split: one wave per token ----
__global__ __launch_bounds__(512) void gatesplit1_k(const float* __restrict__ X,
                                                    const float* __restrict__ GW,
                                                    u16* __restrict__ Xh, u16* __restrict__ Xl,
                                                    int2* __restrict__ e2, float2* __restrict__ w2,
                                                    int* __restrict__ cnt)
{
    __shared__ float gw[F_*E_];           // [e][f]
    for (int i = threadIdx.x; i < F_*E_; i += 512) {
        int f = i >> 3, e = i & 7;
        gw[e*F_ + f] = GW[i];
    }
    __syncthreads();
    int wv = threadIdx.x >> 6, l = threadIdx.x & 63;
    int t = blockIdx.x * 8 + wv;
    const float* xr = X + (size_t)t * F_;
    float a[8];
    #pragma unroll
    for (int e = 0; e < 8; e++) a[e] = 0.f;
    #pragma unroll
    for (int c = 0; c < F_/256; c++) {
        int f = c*256 + l*4;
        float4 x = *(const float4*)(xr + f);
        ushort4 oh, ol;
        fsplit(x.x, oh.x, ol.x); fsplit(x.y, oh.y, ol.y);
        fsplit(x.z, oh.z, ol.z); fsplit(x.w, oh.w, ol.w);
        *(ushort4*)(Xh + (size_t)t*F_ + f) = oh;
        *(ushort4*)(Xl + (size_t)t*F_ + f) = ol;
        #pragma unroll
        for (int e = 0; e < 8; e++) {
            float4 g = *(const float4*)(gw + e*F_ + f);
            a[e] += x.x*g.x + x.y*g.y + x.z*g.z + x.w*g.w;
        }
    }
    #pragma unroll
    for (int e = 0; e < 8; e++) {
        #pragma unroll
        for (int off = 32; off; off >>= 1) a[e] += __shfl_xor(a[e], off);
    }
    if (l == 0) {
        float v0 = -3.4e38f, v1 = -3.4e38f; int i0 = 0, i1 = 0;
        #pragma unroll
        for (int k = 0; k < E_; k++) {
            float v = a[k];
            if (v > v0)      { v1 = v0; i1 = i0; v0 = v; i0 = k; }
            else if (v > v1) { v1 = v;  i1 = k; }
        }
        float ex = expf(v1 - v0);
        e2[t] = make_int2(i0, i1);
        w2[t] = make_float2(1.f/(1.f+ex), ex/(1.f+ex));
        atomicAdd(&cnt[i0], 1);
        atomicAdd(&cnt[i1], 1);
    }
}

// ---- fused gate2 + relu(HC0+HC1) hi/lo split ----
__global__ __launch_bounds__(512) void gatecrelu2_k(const float* __restrict__ A0,
                                                    const float* __restrict__ A1v,
                                                    const float* __restrict__ GW,
                                                    u16* __restrict__ Hh, u16* __restrict__ Hl,
                                                    int2* __restrict__ e2, float2* __restrict__ w2,
                                                    int* __restrict__ cnt)
{
    __shared__ float gw[I_*E_];           // [e][f]
    for (int i = threadIdx.x; i < I_*E_; i += 512) {
        int f = i >> 3, e = i & 7;
        gw[e*I_ + f] = GW[i];
    }
    __syncthreads();
    int wv = threadIdx.x >> 6, l = threadIdx.x & 63;
    int t = blockIdx.x * 8 + wv;
    const float* xr  = A0 + (size_t)t * I_;
    const float* x2r = A1v + (size_t)t * I_;
    float a[8];
    #pragma unroll
    for (int e = 0; e < 8; e++) a[e] = 0.f;
    #pragma unroll
    for (int c = 0; c < I_/256; c++) {
        int f = c*256 + l*4;
        float4 x = *(const float4*)(xr + f);
        float4 y = *(const float4*)(x2r + f);
        x.x = fmaxf(x.x + y.x, 0.f); x.y = fmaxf(x.y + y.y, 0.f);
        x.z = fmaxf(x.z + y.z, 0.f); x.w = fmaxf(x.w + y.w, 0.f);
        ushort4 oh, ol;
        fsplit(x.x, oh.x, ol.x); fsplit(x.y, oh.y, ol.y);
        fsplit(x.z, oh.z, ol.z); fsplit(x.w, oh.w, ol.w);
        *(ushort4*)(Hh + (size_t)t*I_ + f) = oh;
        *(ushort4*)(Hl + (size_t)t*I_ + f) = ol;
        #pragma unroll
        for (int e = 0; e < 8; e++) {
            float4 g = *(const float4*)(gw + e*I_ + f);
            a[e] += x.x*g.x + x.y*g.y + x.z*g.z + x.w*g.w;
        }
    }
    #pragma unroll
    for (int e = 0; e < 8; e++) {
        #pragma unroll
        for (int off = 32; off; off >>= 1) a[e] += __shfl_xor(a[e], off);
    }
    if (l == 0) {
        float v0 = -3.4e38f, v1 = -3.4e38f; int i0 = 0, i1 = 0;
        #pragma unroll
        for (int k = 0; k < E_; k++) {
            float v = a[k];
            if (v > v0)      { v1 = v0; i1 = i0; v0 = v; i0 = k; }
            else if (v > v1) { v1 = v;  i1 = k; }
        }
        float ex = expf(v1 - v0);
        e2[t] = make_int2(i0, i1);
        w2[t] = make_float2(1.f/(1.f+ex), ex/(1.f+ex));
        atomicAdd(&cnt[i0], 1);
        atomicAdd(&cnt[i1], 1);
    }
}

// ---- schedule builder: 1 block; writes entries + pos, pads stok, resets cnt ----
__global__ __launch_bounds__(256) void sched_k(int* __restrict__ cnt, int* __restrict__ pos,
                                               int4* __restrict__ s0, int4* __restrict__ s1,
                                               int split, int* __restrict__ stok)
{
    int tid = threadIdx.x;
    int nb[E_], slotst[E_], gst[E_], cn[E_];
    int poff = 0, g0 = 0, g1 = 0;
    #pragma unroll
    for (int e = 0; e < E_; e++) {
        cn[e] = cnt[e];
        int n = (cn[e] + 127) >> 7;
        nb[e] = n;
        slotst[e] = poff;
        if (e < split) { gst[e] = g0; g0 += n; }
        else           { gst[e] = g1; g1 += n; }
        poff += n << 7;
    }
    if (tid < E_) pos[tid] = slotst[tid];
    for (int j = tid; j < GMAX_; j += 256) {
        int4 en = make_int4(0,0,0,0);
        for (int e = 0; e < split; e++)
            if (j >= gst[e] && j < gst[e] + nb[e])
                en = make_int4(slotst[e] + (j - gst[e])*128, e, 1, 0);
        s0[j] = en;
        if (split < E_) {
            int4 en1 = make_int4(0,0,0,0);
            for (int e = split; e < E_; e++)
                if (j >= gst[e] && j < gst[e] + nb[e])
                    en1 = make_int4(slotst[e] + (j - gst[e])*128, e - split, 1, 0);
            s1[j] = en1;
        }
    }
    // pad slots of this phase -> invalid
    #pragma unroll
    for (int e = 0; e < E_; e++)
        for (int i = slotst[e] + cn[e] + tid; i < slotst[e] + (nb[e] << 7); i += 256)
            stok[i] = -1;
    __syncthreads();
    if (tid < E_) cnt[tid] = 0;     // ready for next gate phase
}

// ---- token scatter (multi-block, global pos; value-deterministic) ----
__global__ void scatter_k(const int2* __restrict__ e2, const float2* __restrict__ w2,
                          int* __restrict__ pos, int* __restrict__ stok, float* __restrict__ sw)
{
    int t = blockIdx.x * 512 + threadIdx.x;
    if (t >= T_) return;
    int2 e = e2[t]; float2 w = w2[t];
    int p0 = atomicAdd(&pos[e.x], 1);
    stok[p0] = t;          sw[p0] = w.x;
    int p1 = atomicAdd(&pos[e.y], 1);
    stok[p1] = t | 4096;   sw[p1] = w.y;
}

// ---- weight transpose: src fp32 (R x C) per z -> dst bf16 hi/lo [z][C][R] ----
__global__ __launch_bounds__(256) void transp_k(const float* __restrict__ src0,
                                                u16* __restrict__ dh, u16* __restrict__ dl,
                                                int R, int C)
{
    __shared__ float tl[32][33];
    int z = blockIdx.z;
    const float* src = src0 + (size_t)z * R * C;
    size_t dbase = (size_t)z * R * C;
    int c0 = blockIdx.x * 32, r0 = blockIdx.y * 32;
    int tx = threadIdx.x & 31, ty = threadIdx.x >> 5;
    #pragma unroll
    for (int j = 0; j < 32; j += 8)
        tl[ty + j][tx] = src[(size_t)(r0 + ty + j) * C + c0 + tx];
    __syncthreads();
    #pragma unroll
    for (int j = 0; j < 32; j += 8) {
        u16 h, l; fsplit(tl[tx][ty + j], h, l);
        size_t idx = dbase + (size_t)(c0 + ty + j) * R + r0 + tx;
        dh[idx] = h; dl[idx] = l;
    }
}

// ---- conv weight: (o,i,k) fp32 -> bf16 hi/lo [o][kc*I + i] ----
__global__ __launch_bounds__(256) void convw_k(const float* __restrict__ src,
                                               u16* __restrict__ dh, u16* __restrict__ dl)
{
    __shared__ float row[KW_*I_];
    int o = blockIdx.x;
    const float* s = src + (size_t)o * (KW_*I_);
    for (int c = threadIdx.x; c < KW_*I_; c += 256) row[c] = s[c];
    __syncthreads();
    size_t base = (size_t)o * (KW_*I_);
    for (int j = threadIdx.x; j < KW_*I_; j += 256) {
        int kc = j >> 10, i = j & 1023;
        u16 h, l; fsplit(row[i*KW_ + kc], h, l);
        dh[base + j] = h; dl[base + j] = l;
    }
}

// ---- generic fp32 -> bf16 hi/lo split (out_w) ----
__global__ void split_k(const float* __restrict__ src, u16* __restrict__ dh, u16* __restrict__ dl)
{
    size_t i = ((size_t)blockIdx.x * 256 + threadIdx.x) * 4;
    float4 v = *(const float4*)(src + i);
    ushort4 oh, ol;
    fsplit(v.x, oh.x, ol.x); fsplit(v.y, oh.y, ol.y);
    fsplit(v.z, oh.z, ol.z); fsplit(v.w, oh.w, ol.w);
    *(ushort4*)(dh + i) = oh;
    *(ushort4*)(dl + i) = ol;
}

// ---- relu(Ha+Hb) -> split -> padded hi/lo ----
__global__ void hsplit_k(const float* __restrict__ Ha, const float* __restrict__ Hb,
                         u16* __restrict__ ph, u16* __restrict__ pl)
{
    int gid = blockIdx.x*256 + threadIdx.x;
    int eb = gid * 4;
    int t = eb >> 10, c = eb & 1023;
    float4 a = *(const float4*)(Ha + eb);
    float4 b = *(const float4*)(Hb + eb);
    ushort4 hh, ll;
    fsplit(fmaxf(a.x+b.x,0.f), hh.x, ll.x); fsplit(fmaxf(a.y+b.y,0.f), hh.y, ll.y);
    fsplit(fmaxf(a.z+b.z,0.f), hh.z, ll.z); fsplit(fmaxf(a.w+b.w,0.f), hh.w, ll.w);
    size_t row = (size_t)(t >> 11)*SP_ + 6 + (t & (S_-1));
    *(ushort4*)(ph + (row << 10) + c) = hh;
    *(ushort4*)(pl + (row << 10) + c) = ll;
}

__global__ void hpadzero_k(u16* __restrict__ ph, u16* __restrict__ pl)
{
    int idx = blockIdx.x*256 + threadIdx.x;   // B_*6*I_
    int b = idx / (6*I_);
    int rem = idx - b*(6*I_);
    size_t a = ((size_t)b*SP_ + (rem >> 10))*I_ + (rem & 1023);
    ph[a] = 0; pl[a] = 0;
}

// =================== split-bf16 MFMA GEMM, 128x128 tile, BK=32 ===================
// SWZ: 0 = none, 1 = conv 2D XCD chunk (grid must be (8,64): 8m x 8n' per XCD)
enum { A_SPLIT=0, A_CONV=1, A_GATHER2=2 };
enum { EP_RANK=0, EP_DUAL=1, EP_FINAL=2 };

#define SBSZ(Pv) ((((Pv)==3)?16384:8192) + 8192*(((Pv)>=2)?2:1))

template<int AM, int EP, int PASSES, int SWZ>
__global__ __launch_bounds__(256, ((2*SBSZ(PASSES)) <= 32768) ? 4 : (((2*SBSZ(PASSES)) <= 49152) ? 3 : 2))
void mgemm(const void* __restrict__ A1, const void* __restrict__ A2,
           const u16* __restrict__ Bh, const u16* __restrict__ Bl,
           float* __restrict__ Ca, float* __restrict__ Cb,
           int N, int Kd, int ldb,
           const int4* __restrict__ sched, const int* __restrict__ stok,
           const float* __restrict__ sw, const float* __restrict__ bias)
{
    constexpr bool HAL = (PASSES==3);
    constexpr bool HBL = (PASSES>=2);
    constexpr int OAL  = 8192;
    constexpr int OBH  = (HAL ? 16384 : 8192);
    constexpr int OBL  = OBH + 8192;
    constexpr int SB   = OBH + 8192*(HBL ? 2 : 1);
    constexpr int NLOADS = 2*(HBL ? 2 : 1) + 2*(HAL ? 2 : 1);
    __shared__ uint4 ldsv[2*SB/16];
    char* lds = (char*)ldsv;

    const int tid  = threadIdx.x;
    const int lane = tid & 63, wid = tid >> 6;
    int n0 = blockIdx.x * 128;

    int slot0 = 0, m0 = 0, koff = 0, kz = 0;
    const u16 *bhb = Bh, *blb = Bl;
    if (AM == A_GATHER2) {
        int4 sc = sched[blockIdx.y];
        if (!sc.z) return;
        slot0 = sc.x;
        size_t wo = (size_t)sc.y * N * ldb;
        bhb = Bh + wo; blb = Bl + wo;
    } else if (AM == A_CONV) {
        if (SWZ == 1) {
            // balanced 2D XCD chunk: XCD = fid&7 owns 8 m-panels x 8 n'-cols
            int fid = blockIdx.y * 8 + blockIdx.x;
            int xcd = fid & 7, k = fid >> 3;
            int mp = (xcd >> 1) * 8 + (k >> 3);          // 0..31
            int np = (xcd & 1) * 8 + (k & 7);            // 0..15  (n' = bx + 8*kz)
            m0 = mp * 128;
            kz = np >> 3;
            koff = kz * Kd;
            n0 = (np & 7) * 128;
        } else {
            m0 = (blockIdx.y & 31) * 128;
            kz = blockIdx.y >> 5;
            koff = kz * Kd;
        }
    } else {
        m0 = blockIdx.y * 128;
    }

    // staging geometry
    int srow[2], klog[2];
    #pragma unroll
    for (int c = 0; c < 2; c++) {
        int row = (tid >> 2) + c*64;
        srow[c] = row;
        klog[c] = ((tid & 3) ^ ((row >> 1) & 3)) << 3;
    }

    const u16 *bgh[2], *bgl[2];
    #pragma unroll
    for (int c = 0; c < 2; c++) {
        size_t off = (size_t)(n0 + srow[c]) * ldb + koff + klog[c];
        bgh[c] = bhb + off;
        bgl[c] = blb + off;
    }

    const u16 *a1p[2], *a2p[2];
    #pragma unroll
    for (int c = 0; c < 2; c++) {
        if (AM == A_SPLIT) {
            size_t off = (size_t)(m0 + srow[c]) * Kd + klog[c];
            a1p[c] = (const u16*)A1 + off;
            a2p[c] = (const u16*)A2 + off;
        } else if (AM == A_CONV) {
            int t = m0 + srow[c];
            size_t rb = (((size_t)(t >> 11)*SP_ + (t & (S_-1))) << 10) + koff + klog[c];
            a1p[c] = (const u16*)A1 + rb;
            a2p[c] = (const u16*)A2 + rb;
        } else { // A_GATHER2
            int s = stok[slot0 + srow[c]];
            int tk = (s < 0) ? 0 : (s & 4095);
            size_t off = (size_t)tk * Kd + klog[c];
            a1p[c] = (const u16*)A1 + off;
            a2p[c] = (const u16*)A2 + off;
        }
    }

    // fragment read offsets (swizzle matches staging); 4 waves as 2x2 of 64x64
    const int wr = wid >> 1, wc = wid & 1;
    const int l15 = lane & 15, kq = lane >> 4;
    int aoff[4], boff[4];
    #pragma unroll
    for (int m = 0; m < 4; m++) {
        int ra = wr*64 + m*16 + l15;
        aoff[m] = ra*64 + ((kq ^ ((ra >> 1) & 3)) << 4);
    }
    #pragma unroll
    for (int n = 0; n < 4; n++) {
        int rb = wc*64 + n*16 + l15;
        boff[n] = rb*64 + ((kq ^ ((rb >> 1) & 3)) << 4);
    }

    f32x4 acc[4][4];
    #pragma unroll
    for (int m = 0; m < 4; m++)
        #pragma unroll
        for (int n = 0; n < 4; n++) acc[m][n] = {0.f,0.f,0.f,0.f};

    const int nt = Kd >> 5;

#define STAGE_GL(K0, BB)                                                          \
    {                                                                             \
        _Pragma("unroll")                                                         \
        for (int c = 0; c < 2; c++) {                                             \
            GLDS16(bgh[c] + (K0), lds + (BB) + OBH + c*4096 + (wid<<10));         \
            if (HBL)                                                              \
                GLDS16(bgl[c] + (K0), lds + (BB) + OBL + c*4096 + (wid<<10));     \
        }                                                                         \
        _Pragma("unroll")                                                         \
        for (int c = 0; c < 2; c++) {                                             \
            GLDS16(a1p[c] + (K0), lds + (BB) + c*4096 + (wid<<10));               \
            if (HAL)                                                              \
                GLDS16(a2p[c] + (K0), lds + (BB) + OAL + c*4096 + (wid<<10));     \
        }                                                                         \
    }

    // prologue: 2-deep prefetch
    STAGE_GL(0, 0);
    STAGE_GL(32, SB);
    waitvm<NLOADS>();
    __builtin_amdgcn_s_barrier();

    for (int it = 0; it < nt; ++it) {
        const int bb = (it & 1) * SB;
        {
            bf16x8 ah[4], al[4], bhf[4], blf[4];
            #pragma unroll
            for (int m = 0; m < 4; m++) {
                ah[m] = *(const bf16x8*)(lds + bb + aoff[m]);
                if (HAL) al[m] = *(const bf16x8*)(lds + bb + OAL + aoff[m]);
            }
            #pragma unroll
            for (int n = 0; n < 4; n++) {
                bhf[n] = *(const bf16x8*)(lds + bb + OBH + boff[n]);
                if (HBL) blf[n] = *(const bf16x8*)(lds + bb + OBL + boff[n]);
            }
            __builtin_amdgcn_s_setprio(1);
            #pragma unroll
            for (int m = 0; m < 4; m++)
                #pragma unroll
                for (int n = 0; n < 4; n++) {
                    acc[m][n] = __builtin_amdgcn_mfma_f32_16x16x32_bf16(ah[m], bhf[n], acc[m][n], 0, 0, 0);
                    if (HAL)
                        acc[m][n] = __builtin_amdgcn_mfma_f32_16x16x32_bf16(al[m], bhf[n], acc[m][n], 0, 0, 0);
                    if (HBL)
                        acc[m][n] = __builtin_amdgcn_mfma_f32_16x16x32_bf16(ah[m], blf[n], acc[m][n], 0, 0, 0);
                }
            __builtin_amdgcn_s_setprio(0);
        }
        asm volatile("s_waitcnt lgkmcnt(0)" ::: "memory");
        __builtin_amdgcn_sched_barrier(0);
        __builtin_amdgcn_s_barrier();
        if (it + 2 < nt) {
            STAGE_GL((it + 2) << 5, bb);
            waitvm<NLOADS>();
            __builtin_amdgcn_s_barrier();
        } else if (it + 1 < nt) {
            waitvm<0>();
            __builtin_amdgcn_s_barrier();
        }
    }

    // epilogue: C/D layout col=lane&15, row=(lane>>4)*4+reg
    #pragma unroll
    for (int m = 0; m < 4; m++) {
        #pragma unroll
        for (int n = 0; n < 4; n++) {
            f32x4 v = acc[m][n];
            int rl0 = wr*64 + m*16 + (lane >> 4)*4;
            int col = n0 + wc*64 + n*16 + l15;
            #pragma unroll
            for (int j = 0; j < 4; j++) {
                float x = v[j];
                int rl = rl0 + j;
                if (EP == EP_RANK) {
                    int s = stok[slot0 + rl];
                    if (s >= 0) {
                        int tt = s & 4095;
                        float ww = sw[slot0 + rl];
                        float* dst = (s & 4096) ? Cb : Ca;
                        dst[(size_t)tt * N + col] = ww * x;
                    }
                } else if (EP == EP_DUAL) {
                    int r = m0 + rl;
                    float* dst = kz ? Cb : Ca;
                    dst[(size_t)r * N + col] = x;
                } else { // EP_FINAL
                    int r = m0 + rl;
                    x += bias[r];
                    int b = col >> 11, s = col & (S_-1);
                    Ca[(((size_t)(b*CLASSES_ + r)) << 11) + s] = x;
                }
            }
        }
    }
#undef STAGE_GL
}

// ---------------- chunked cumsum over Oa+Ob ----------------
#define SC_ 128
#define NCH_ (S_/SC_)
__global__ void cum1(const float* __restrict__ Oa, const float* __restrict__ Ob,
                     float* __restrict__ CS)
{
    int blk = blockIdx.x;
    int b = blk / NCH_, ch = blk % NCH_;
    int c = threadIdx.x;
    int s0 = ch * SC_;
    size_t base = ((size_t)(b*S_ + s0)) * (3*F_) + c;
    float sum = 0.f;
    for (int s = 0; s < SC_; s++) {
        size_t idx = base + (size_t)s * (3*F_);
        sum += Oa[idx] + Ob[idx];
    }
    CS[(size_t)blk * F_ + c] = sum;
}
__global__ void cum23(const float* __restrict__ Oa, const float* __restrict__ Ob,
                      const float* __restrict__ CS, float* __restrict__ FP)
{
    int blk = blockIdx.x;
    int b = blk / NCH_, ch = blk % NCH_;
    int c = threadIdx.x;
    float run = 0.f;
    for (int j = 0; j < ch; j++) run += CS[(size_t)(b*NCH_ + j) * F_ + c];
    int s0 = ch * SC_;
    for (int s = s0; s < s0 + SC_; s++) {
        size_t t = (size_t)b * S_ + s;
        size_t ro = t * (3*F_);
        run += Oa[ro + c] + Ob[ro + c];
        float scl = Oa[ro + F_ + c] + Ob[ro + F_ + c];
        float shf = Oa[ro + 2*F_ + c] + Ob[ro + 2*F_ + c];
        FP[t*F_ + c] = run / (float)(s + 1) * scl + shf;
    }
}

// ---------------- fused norm + recurrence ----------------
__global__ __launch_bounds__(256) void normupd_k(const float* __restrict__ FP,
                                                 float* __restrict__ X0, float* __restrict__ X1)
{
    __shared__ float sb[4];
    int t = blockIdx.x;
    const float* row = FP + (size_t)t * F_;
    int tid = threadIdx.x;
    float v0 = row[tid], v1 = row[tid + 256];
    float s = v0 + v1;
    #pragma unroll
    for (int off = 32; off; off >>= 1) s += __shfl_xor(s, off);
    int w = tid >> 6;
    if ((tid & 63) == 0) sb[w] = s;
    __syncthreads();
    float mean = (sb[0] + sb[1] + sb[2] + sb[3]) * (1.0f / F_);
    v0 -= mean; v1 -= mean;
    float q = v0*v0 + v1*v1;
    #pragma unroll
    for (int off = 32; off; off >>= 1) q += __shfl_xor(q, off);
    __syncthreads();
    if ((tid & 63) == 0) sb[w] = q;
    __syncthreads();
    float ss = sb[0] + sb[1] + sb[2] + sb[3];
    float denom = sqrtf(ss) * 0.04419417382415922f + 1e-5f;
    float sc = 0.70710678118654752f / denom;
    float f0 = v0 * sc, f1 = v1 * sc;
    size_t i0 = (size_t)t * F_ + tid, i1 = i0 + 256;
    float a0 = 0.9f * X0[i0] + 0.1f * f0;
    float a1 = 0.9f * X0[i1] + 0.1f * f1;
    X0[i0] = a0; X1[i0] += a0;
    X0[i1] = a1; X1[i1] += a1;
}

__global__ void concat_k(const float* __restrict__ X0, const float* __restrict__ X1,
                         u16* __restrict__ Xh, u16* __restrict__ Xl)
{
    int t = blockIdx.x;
    for (int c = threadIdx.x; c < F_; c += 256) {
        u16 h, l;
        fsplit(X0[(size_t)t*F_ + c], h, l);
        Xh[(size_t)t*(2*F_) + c] = h;      Xl[(size_t)t*(2*F_) + c] = l;
        fsplit(X1[(size_t)t*F_ + c], h, l);
        Xh[(size_t)t*(2*F_) + F_ + c] = h; Xl[(size_t)t*(2*F_) + F_ + c] = l;
    }
}

extern "C" void kernel_launch(void* const* d_in, const int* in_sizes, int n_in,
                              void* d_out, int out_size, void* d_ws, size_t ws_size,
                              hipStream_t stream)
{
    const int*   inp    = (const int*)  d_in[0];
    const float* embed  = (const float*)d_in[1];
    const float* gin_w  = (const float*)d_in[2];
    const float* w_in   = (const float*)d_in[3];
    const float* conv_w = (const float*)d_in[4];
    const float* gout_w = (const float*)d_in[5];
    const float* w_out  = (const float*)d_in[6];
    const float* out_w  = (const float*)d_in[7];
    const float* out_b  = (const float*)d_in[8];
    float* out = (float*)d_out;

    char* w = (char*)d_ws;
    auto alloc = [&](size_t bytes) { char* r = w; w += (bytes + 255) & ~(size_t)255; return r; };
    float* X0    = (float*)alloc((size_t)T_*F_*4);
    float* X1    = (float*)alloc((size_t)T_*F_*4);
    u16*   Hpadh = (u16*)  alloc((size_t)B_*SP_*I_*2);      // pair (reused as OutWl)
    u16*   Hpadl = (u16*)  alloc((size_t)B_*SP_*I_*2);
    u16*   HCh   = (u16*)  alloc((size_t)T_*I_*2);
    u16*   HCl   = (u16*)  alloc((size_t)T_*I_*2);
    float* FP    = (float*)alloc((size_t)T_*F_*4);          // also X1h|X1l during MoE1
    float* CS    = (float*)alloc((size_t)B_*NCH_*F_*4);
    char*  ar1   = alloc((size_t)T_*3*F_*4);                // Ha / Oa / Xcat h,l
    char*  ar2   = alloc((size_t)T_*I_*4);                  // HC0 / OutWh
    char*  altr  = alloc((size_t)T_*3*F_*4);                // Hb / HC1 / Ob
    u16*   Wh    = (u16*)  alloc((size_t)I_*KW_*I_*2);
    u16*   Wl    = (u16*)  alloc((size_t)I_*KW_*I_*2);
    int2*  e2    = (int2*) alloc((size_t)T_*8);
    float2* w2   = (float2*)alloc((size_t)T_*8);
    int*   stok  = (int*)  alloc((size_t)NSLOT_*4);
    float* sw    = (float*)alloc((size_t)NSLOT_*4);
    int*   cnt   = (int*)  alloc(64);
    int*   pos   = (int*)  alloc(64);
    int4*  s0    = (int4*) alloc((size_t)GMAX_*16);
    int4*  s1    = (int4*) alloc((size_t)GMAX_*16);

    float* Ha  = (float*)ar1;
    float* Oa  = (float*)ar1;
    float* HC0 = (float*)ar2;
    float* Hb  = (float*)altr;
    float* HC1 = (float*)altr;
    float* Ob  = (float*)altr;
    u16*   X1h = (u16*)FP;                 // FP region dead during MoE1 phase
    u16*   X1l = X1h + (size_t)T_*F_;

    embed_k<<<T_, 256, 0, stream>>>(inp, embed, X0, X1);
    hpadzero_k<<<(B_*6*I_)/256, 256, 0, stream>>>(Hpadh, Hpadl);
    initslot_k<<<(NSLOT_+255)/256, 256, 0, stream>>>(stok, cnt);   // once; sched_k maintains

    for (int d = 0; d < D_; ++d) {
        // ---------- MoE1 (fused gate+split, sparse gather, rank-split stores) ----------
        gatesplit1_k<<<T_/8, 512, 0, stream>>>(X1, gin_w + (size_t)d*F_*E_,
                                               X1h, X1l, e2, w2, cnt);
        sched_k<<<1, 256, 0, stream>>>(cnt, pos, s0, s1, 8, stok);
        scatter_k<<<T_/512, 512, 0, stream>>>(e2, w2, pos, stok, sw);
        transp_k<<<dim3(I_/32, F_/32, E_), 256, 0, stream>>>(
            w_in + (size_t)d*E_*F_*I_, Wh, Wl, F_, I_);
        mgemm<A_GATHER2, EP_RANK, 3, 0><<<dim3(I_/128, GMAX_), 256, 0, stream>>>(
            X1h, X1l, Wh, Wl, Ha, Hb, I_, F_, F_, s0, stok, sw, nullptr);
        hsplit_k<<<T_*I_/1024, 256, 0, stream>>>(Ha, Hb, Hpadh, Hpadl);

        // ---------- causal conv (dense, K-split 2, XCD-chunked, dual plain-store) ----------
        convw_k<<<I_, 256, 0, stream>>>(conv_w + (size_t)d*I_*I_*KW_, Wh, Wl);
        mgemm<A_CONV, EP_DUAL, 3, 1><<<dim3(8, 64), 256, 0, stream>>>(
            Hpadh, Hpadl, Wh, Wl, HC0, HC1, I_, (KW_*I_)/2, KW_*I_, nullptr, nullptr, nullptr, nullptr);

        // ---------- MoE2 (fused gate+crelu, sparse gather, rank-split stores) ----------
        gatecrelu2_k<<<T_/8, 512, 0, stream>>>(HC0, HC1, gout_w + (size_t)d*I_*E_,
                                               HCh, HCl, e2, w2, cnt);
        sched_k<<<1, 256, 0, stream>>>(cnt, pos, s0, s1, 4, stok);
        scatter_k<<<T_/512, 512, 0, stream>>>(e2, w2, pos, stok, sw);
        for (int c = 0; c < 2; ++c) {
            transp_k<<<dim3((3*F_)/32, I_/32, 4), 256, 0, stream>>>(
                w_out + (size_t)d*E_*I_*(3*F_) + (size_t)c*4*I_*(3*F_), Wh, Wl, I_, 3*F_);
            const int4* sc = (c == 0) ? s0 : s1;
            if (d == 0)
                mgemm<A_GATHER2, EP_RANK, 3, 0><<<dim3((3*F_)/128, GMAX_), 256, 0, stream>>>(
                    HCh, HCl, Wh, Wl, Oa, Ob, 3*F_, I_, I_, sc, stok, sw, nullptr);
            else
                mgemm<A_GATHER2, EP_RANK, 1, 0><<<dim3((3*F_)/128, GMAX_), 256, 0, stream>>>(
                    HCh, HCl, Wh, Wl, Oa, Ob, 3*F_, I_, I_, sc, stok, sw, nullptr);
        }

        cum1<<<B_*NCH_, F_, 0, stream>>>(Oa, Ob, CS);
        cum23<<<B_*NCH_, F_, 0, stream>>>(Oa, Ob, CS, FP);
        normupd_k<<<T_, 256, 0, stream>>>(FP, X0, X1);
    }

    // ---------- final vocab GEMM (2-pass: OWh.Xh + OWh.Xl) ----------
    u16* Xch  = (u16*)ar1;
    u16* Xcl  = (u16*)(ar1 + (size_t)T_*(2*F_)*2);
    u16* OWh  = (u16*)ar2;
    u16* OWl  = Hpadh;   // unused by the 2-pass kernel but valid memory

    concat_k<<<T_, 256, 0, stream>>>(X0, X1, Xch, Xcl);
    split_k<<<(CLASSES_*2*F_)/1024, 256, 0, stream>>>(out_w, OWh, OWl);
    mgemm<A_SPLIT, EP_FINAL, 2, 0><<<dim3(T_/128, CLASSES_/128), 256, 0, stream>>>(
        OWh, OWl, Xch, Xcl, out, nullptr, T_, 2*F_, 2*F_, nullptr, nullptr, nullptr, out_b);
}

// Round 11
// 1466.419 us; speedup vs baseline: 1.0834x; 1.0834x over previous
//
#include <hip/hip_runtime.h>
#include <math.h>

typedef unsigned short u16;
typedef unsigned int   u32;

#define B_ 2
#define S_ 2048
#define F_ 512
#define I_ 1024
#define E_ 8
#define KW_ 7
#define D_ 2
#define CLASSES_ 8192
#define T_ (B_*S_)
#define SP_ (S_+6)
#define NSLOT_ 9216
#define GMAX_ 72

typedef __bf16 bf16x8 __attribute__((ext_vector_type(8)));
typedef float  f32x4  __attribute__((ext_vector_type(4)));

__device__ __forceinline__ u16 f2b(float f) {
    u32 x = __float_as_uint(f);
    return (u16)((x + 0x7fffu + ((x >> 16) & 1u)) >> 16);
}
__device__ __forceinline__ void fsplit(float v, u16& h, u16& l) {
    u16 hh = f2b(v);
    float hv = __uint_as_float(((u32)hh) << 16);
    h = hh;
    l = f2b(v - hv);
}

template<int N> __device__ __forceinline__ void waitvm() {
    asm volatile("s_waitcnt vmcnt(%0)" :: "n"(N) : "memory");
}

#define GLDS16(g, l) __builtin_amdgcn_global_load_lds( \
    (const __attribute__((address_space(1))) u32*)(g), \
    (__attribute__((address_space(3))) u32*)(l), 16, 0, 0)

// ---------------- misc small kernels ----------------
__global__ void embed_k(const int* __restrict__ inp, const float* __restrict__ emb,
                        float* __restrict__ X0, float* __restrict__ X1)
{
    int t = blockIdx.x;
    int r = inp[t];
    const float* e = emb + (size_t)r * (2*F_);
    for (int c = threadIdx.x; c < F_; c += 256) {
        X0[(size_t)t*F_ + c] = e[c];
        X1[(size_t)t*F_ + c] = e[F_ + c];
    }
}

// reset slot map (-1 = invalid) + expert counters
__global__ void initslot_k(int* __restrict__ stok, int* __restrict__ cnt)
{
    int i = blockIdx.x*256 + threadIdx.x;
    if (i < NSLOT_) stok[i] = -1;
    if (i < E_) cnt[i] = 0;
}

// vectorized gate + top2: one wave per token, GW transposed in LDS.
// MODE 1: input = relu(X[f] + X2[f])
template<int MODE, int W>
__global__ __launch_bounds__(512) void gatev_k(const float* __restrict__ X,
                                               const float* __restrict__ X2,
                                               const float* __restrict__ GW,
                                               int2* __restrict__ e2, float2* __restrict__ w2,
                                               int* __restrict__ cnt)
{
    __shared__ float gw[W*E_];            // [e][f]
    for (int i = threadIdx.x; i < W*E_; i += 512) {
        int f = i >> 3, e = i & 7;
        gw[e*W + f] = GW[i];
    }
    __syncthreads();
    int wv = threadIdx.x >> 6, l = threadIdx.x & 63;
    int t = blockIdx.x * 8 + wv;
    const float* xr  = X + (size_t)t * W;
    const float* x2r = MODE ? (X2 + (size_t)t * W) : nullptr;
    float a[8];
    #pragma unroll
    for (int e = 0; e < 8; e++) a[e] = 0.f;
    #pragma unroll
    for (int c = 0; c < W/256; c++) {
        int f = c*256 + l*4;
        float4 x = *(const float4*)(xr + f);
        if (MODE) {
            float4 y = *(const float4*)(x2r + f);
            x.x = fmaxf(x.x + y.x, 0.f); x.y = fmaxf(x.y + y.y, 0.f);
            x.z = fmaxf(x.z + y.z, 0.f); x.w = fmaxf(x.w + y.w, 0.f);
        }
        #pragma unroll
        for (int e = 0; e < 8; e++) {
            float4 g = *(const float4*)(gw + e*W + f);
            a[e] += x.x*g.x + x.y*g.y + x.z*g.z + x.w*g.w;
        }
    }
    #pragma unroll
    for (int e = 0; e < 8; e++) {
        #pragma unroll
        for (int off = 32; off; off >>= 1) a[e] += __shfl_xor(a[e], off);
    }
    if (l == 0) {
        float v0 = -3.4e38f, v1 = -3.4e38f; int i0 = 0, i1 = 0;
        #pragma unroll
        for (int k = 0; k < E_; k++) {
            float v = a[k];
            if (v > v0)      { v1 = v0; i1 = i0; v0 = v; i0 = k; }
            else if (v > v1) { v1 = v;  i1 = k; }
        }
        float ex = expf(v1 - v0);
        e2[t] = make_int2(i0, i1);
        w2[t] = make_float2(1.f/(1.f+ex), ex/(1.f+ex));
        atomicAdd(&cnt[i0], 1);
        atomicAdd(&cnt[i1], 1);
    }
}

// fused schedule build + token scatter; one block. stok = t | (rank<<12)
__global__ __launch_bounds__(256) void schedscat_k(const int* __restrict__ cnt,
                                                   const int2* __restrict__ e2,
                                                   const float2* __restrict__ w2,
                                                   int4* __restrict__ s0, int4* __restrict__ s1,
                                                   int split,
                                                   int* __restrict__ stok, float* __restrict__ sw)
{
    __shared__ int lpos[E_];
    int tid = threadIdx.x;
    int nb[E_], slotst[E_], gst[E_];
    int poff = 0, g0 = 0, g1 = 0;
    #pragma unroll
    for (int e = 0; e < E_; e++) {
        int n = (cnt[e] + 127) >> 7;
        nb[e] = n;
        slotst[e] = poff;
        if (e < split) { gst[e] = g0; g0 += n; }
        else           { gst[e] = g1; g1 += n; }
        poff += n << 7;
    }
    if (tid < E_) lpos[tid] = slotst[tid];
    if (tid < GMAX_) {
        int4 en = make_int4(0,0,0,0);
        for (int e = 0; e < split; e++)
            if (tid >= gst[e] && tid < gst[e] + nb[e])
                en = make_int4(slotst[e] + (tid - gst[e])*128, e, 1, 0);
        s0[tid] = en;
    }
    if (split < E_ && tid >= 128 && tid < 128 + GMAX_) {
        int j = tid - 128;
        int4 en = make_int4(0,0,0,0);
        for (int e = split; e < E_; e++)
            if (j >= gst[e] && j < gst[e] + nb[e])
                en = make_int4(slotst[e] + (j - gst[e])*128, e - split, 1, 0);
        s1[j] = en;
    }
    __syncthreads();
    for (int t = tid; t < T_; t += 256) {
        int2 e = e2[t]; float2 w = w2[t];
        int p0 = atomicAdd(&lpos[e.x], 1);
        stok[p0] = t;          sw[p0] = w.x;      // rank 0
        int p1 = atomicAdd(&lpos[e.y], 1);
        stok[p1] = t | 4096;   sw[p1] = w.y;      // rank 1
    }
}

// ---- weight transpose: src fp32 (R x C) per z -> dst bf16 hi/lo [z][C][R] ----
__global__ __launch_bounds__(256) void transp_k(const float* __restrict__ src0,
                                                u16* __restrict__ dh, u16* __restrict__ dl,
                                                int R, int C)
{
    __shared__ float tl[32][33];
    int z = blockIdx.z;
    const float* src = src0 + (size_t)z * R * C;
    size_t dbase = (size_t)z * R * C;
    int c0 = blockIdx.x * 32, r0 = blockIdx.y * 32;
    int tx = threadIdx.x & 31, ty = threadIdx.x >> 5;
    #pragma unroll
    for (int j = 0; j < 32; j += 8)
        tl[ty + j][tx] = src[(size_t)(r0 + ty + j) * C + c0 + tx];
    __syncthreads();
    #pragma unroll
    for (int j = 0; j < 32; j += 8) {
        u16 h, l; fsplit(tl[tx][ty + j], h, l);
        size_t idx = dbase + (size_t)(c0 + ty + j) * R + r0 + tx;
        dh[idx] = h; dl[idx] = l;
    }
}

// ---- conv weight: (o,i,k) fp32 -> bf16 hi/lo [o][kc*I + i] ----
__global__ __launch_bounds__(256) void convw_k(const float* __restrict__ src,
                                               u16* __restrict__ dh, u16* __restrict__ dl)
{
    __shared__ float row[KW_*I_];
    int o = blockIdx.x;
    const float* s = src + (size_t)o * (KW_*I_);
    for (int c = threadIdx.x; c < KW_*I_; c += 256) row[c] = s[c];
    __syncthreads();
    size_t base = (size_t)o * (KW_*I_);
    for (int j = threadIdx.x; j < KW_*I_; j += 256) {
        int kc = j >> 10, i = j & 1023;
        u16 h, l; fsplit(row[i*KW_ + kc], h, l);
        dh[base + j] = h; dl[base + j] = l;
    }
}

// ---- generic fp32 -> bf16 hi/lo split ----
__global__ void split_k(const float* __restrict__ src, u16* __restrict__ dh, u16* __restrict__ dl)
{
    size_t i = ((size_t)blockIdx.x * 256 + threadIdx.x) * 4;
    float4 v = *(const float4*)(src + i);
    ushort4 oh, ol;
    fsplit(v.x, oh.x, ol.x); fsplit(v.y, oh.y, ol.y);
    fsplit(v.z, oh.z, ol.z); fsplit(v.w, oh.w, ol.w);
    *(ushort4*)(dh + i) = oh;
    *(ushort4*)(dl + i) = ol;
}

// ---- relu(Ha+Hb) -> split -> padded hi/lo ----
__global__ void hsplit_k(const float* __restrict__ Ha, const float* __restrict__ Hb,
                         u16* __restrict__ ph, u16* __restrict__ pl)
{
    int gid = blockIdx.x*256 + threadIdx.x;
    int eb = gid * 4;
    int t = eb >> 10, c = eb & 1023;
    float4 a = *(const float4*)(Ha + eb);
    float4 b = *(const float4*)(Hb + eb);
    ushort4 hh, ll;
    fsplit(fmaxf(a.x+b.x,0.f), hh.x, ll.x); fsplit(fmaxf(a.y+b.y,0.f), hh.y, ll.y);
    fsplit(fmaxf(a.z+b.z,0.f), hh.z, ll.z); fsplit(fmaxf(a.w+b.w,0.f), hh.w, ll.w);
    size_t row = (size_t)(t >> 11)*SP_ + 6 + (t & (S_-1));
    *(ushort4*)(ph + (row << 10) + c) = hh;
    *(ushort4*)(pl + (row << 10) + c) = ll;
}

// ---- relu(HC0+HC1) -> split (flat) ----
__global__ void crelu_k(const float* __restrict__ a0, const float* __restrict__ a1,
                        u16* __restrict__ dh, u16* __restrict__ dl)
{
    size_t i = ((size_t)blockIdx.x * 256 + threadIdx.x) * 4;
    float4 a = *(const float4*)(a0 + i);
    float4 b = *(const float4*)(a1 + i);
    ushort4 hh, ll;
    fsplit(fmaxf(a.x+b.x,0.f), hh.x, ll.x); fsplit(fmaxf(a.y+b.y,0.f), hh.y, ll.y);
    fsplit(fmaxf(a.z+b.z,0.f), hh.z, ll.z); fsplit(fmaxf(a.w+b.w,0.f), hh.w, ll.w);
    *(ushort4*)(dh + i) = hh;
    *(ushort4*)(dl + i) = ll;
}

__global__ void hpadzero_k(u16* __restrict__ ph, u16* __restrict__ pl)
{
    int idx = blockIdx.x*256 + threadIdx.x;   // B_*6*I_
    int b = idx / (6*I_);
    int rem = idx - b*(6*I_);
    size_t a = ((size_t)b*SP_ + (rem >> 10))*I_ + (rem & 1023);
    ph[a] = 0; pl[a] = 0;
}

// =================== split-bf16 MFMA GEMM, 128x128 tile, BK=32 ===================
// Counted-vmcnt 2-deep pipeline; per-wave 64x64 output.
// SWZ=1 (conv only): balanced 2D XCD chunk, grid must be (8,64).
// PRIO=1 (conv only): s_setprio around the MFMA cluster.
enum { A_SPLIT=0, A_CONV=1, A_GATHER2=2 };
enum { EP_RANK=0, EP_DUAL=1, EP_FINAL=2 };

#define SBSZ(Pv) ((((Pv)==3)?16384:8192) + 8192*(((Pv)>=2)?2:1))

template<int AM, int EP, int PASSES, int SWZ, int PRIO>
__global__ __launch_bounds__(256, ((2*SBSZ(PASSES)) <= 32768) ? 4 : (((2*SBSZ(PASSES)) <= 49152) ? 3 : 2))
void mgemm(const void* __restrict__ A1, const void* __restrict__ A2,
           const u16* __restrict__ Bh, const u16* __restrict__ Bl,
           float* __restrict__ Ca, float* __restrict__ Cb,
           int N, int Kd, int ldb,
           const int4* __restrict__ sched, const int* __restrict__ stok,
           const float* __restrict__ sw, const float* __restrict__ bias)
{
    constexpr bool HAL = (PASSES==3);
    constexpr bool HBL = (PASSES>=2);
    constexpr int OAL  = 8192;
    constexpr int OBH  = (HAL ? 16384 : 8192);
    constexpr int OBL  = OBH + 8192;
    constexpr int SB   = OBH + 8192*(HBL ? 2 : 1);
    constexpr int NLOADS = 2*(HBL ? 2 : 1) + 2*(HAL ? 2 : 1);
    __shared__ uint4 ldsv[2*SB/16];
    char* lds = (char*)ldsv;

    const int tid  = threadIdx.x;
    const int lane = tid & 63, wid = tid >> 6;
    int n0 = blockIdx.x * 128;

    int slot0 = 0, m0 = 0, koff = 0, kz = 0;
    const u16 *bhb = Bh, *blb = Bl;
    if (AM == A_GATHER2) {
        int4 sc = sched[blockIdx.y];
        if (!sc.z) return;
        slot0 = sc.x;
        size_t wo = (size_t)sc.y * N * ldb;
        bhb = Bh + wo; blb = Bl + wo;
    } else if (AM == A_CONV) {
        if (SWZ == 1) {
            int fid = blockIdx.y * 8 + blockIdx.x;
            int xcd = fid & 7, k = fid >> 3;
            int mp = (xcd >> 1) * 8 + (k >> 3);          // 0..31
            int np = (xcd & 1) * 8 + (k & 7);            // 0..15
            m0 = mp * 128;
            kz = np >> 3;
            koff = kz * Kd;
            n0 = (np & 7) * 128;
        } else {
            m0 = (blockIdx.y & 31) * 128;
            kz = blockIdx.y >> 5;
            koff = kz * Kd;
        }
    } else {
        m0 = blockIdx.y * 128;
    }

    // staging geometry
    int srow[2], klog[2];
    #pragma unroll
    for (int c = 0; c < 2; c++) {
        int row = (tid >> 2) + c*64;
        srow[c] = row;
        klog[c] = ((tid & 3) ^ ((row >> 1) & 3)) << 3;
    }

    const u16 *bgh[2], *bgl[2];
    #pragma unroll
    for (int c = 0; c < 2; c++) {
        size_t off = (size_t)(n0 + srow[c]) * ldb + koff + klog[c];
        bgh[c] = bhb + off;
        bgl[c] = blb + off;
    }

    const u16 *a1p[2], *a2p[2];
    #pragma unroll
    for (int c = 0; c < 2; c++) {
        if (AM == A_SPLIT) {
            size_t off = (size_t)(m0 + srow[c]) * Kd + klog[c];
            a1p[c] = (const u16*)A1 + off;
            a2p[c] = (const u16*)A2 + off;
        } else if (AM == A_CONV) {
            int t = m0 + srow[c];
            size_t rb = (((size_t)(t >> 11)*SP_ + (t & (S_-1))) << 10) + koff + klog[c];
            a1p[c] = (const u16*)A1 + rb;
            a2p[c] = (const u16*)A2 + rb;
        } else { // A_GATHER2
            int s = stok[slot0 + srow[c]];
            int tk = (s < 0) ? 0 : (s & 4095);
            size_t off = (size_t)tk * Kd + klog[c];
            a1p[c] = (const u16*)A1 + off;
            a2p[c] = (const u16*)A2 + off;
        }
    }

    // fragment read offsets (swizzle matches staging); 4 waves as 2x2 of 64x64
    const int wr = wid >> 1, wc = wid & 1;
    const int l15 = lane & 15, kq = lane >> 4;
    int aoff[4], boff[4];
    #pragma unroll
    for (int m = 0; m < 4; m++) {
        int ra = wr*64 + m*16 + l15;
        aoff[m] = ra*64 + ((kq ^ ((ra >> 1) & 3)) << 4);
    }
    #pragma unroll
    for (int n = 0; n < 4; n++) {
        int rb = wc*64 + n*16 + l15;
        boff[n] = rb*64 + ((kq ^ ((rb >> 1) & 3)) << 4);
    }

    f32x4 acc[4][4];
    #pragma unroll
    for (int m = 0; m < 4; m++)
        #pragma unroll
        for (int n = 0; n < 4; n++) acc[m][n] = {0.f,0.f,0.f,0.f};

    const int nt = Kd >> 5;

#define STAGE_GL(K0, BB)                                                          \
    {                                                                             \
        _Pragma("unroll")                                                         \
        for (int c = 0; c < 2; c++) {                                             \
            GLDS16(bgh[c] + (K0), lds + (BB) + OBH + c*4096 + (wid<<10));         \
            if (HBL)                                                              \
                GLDS16(bgl[c] + (K0), lds + (BB) + OBL + c*4096 + (wid<<10));     \
        }                                                                         \
        _Pragma("unroll")                                                         \
        for (int c = 0; c < 2; c++) {                                             \
            GLDS16(a1p[c] + (K0), lds + (BB) + c*4096 + (wid<<10));               \
            if (HAL)                                                              \
                GLDS16(a2p[c] + (K0), lds + (BB) + OAL + c*4096 + (wid<<10));     \
        }                                                                         \
    }

    // prologue: 2-deep prefetch
    STAGE_GL(0, 0);
    STAGE_GL(32, SB);
    waitvm<NLOADS>();
    __builtin_amdgcn_s_barrier();

    for (int it = 0; it < nt; ++it) {
        const int bb = (it & 1) * SB;
        {
            bf16x8 ah[4], al[4], bhf[4], blf[4];
            #pragma unroll
            for (int m = 0; m < 4; m++) {
                ah[m] = *(const bf16x8*)(lds + bb + aoff[m]);
                if (HAL) al[m] = *(const bf16x8*)(lds + bb + OAL + aoff[m]);
            }
            #pragma unroll
            for (int n = 0; n < 4; n++) {
                bhf[n] = *(const bf16x8*)(lds + bb + OBH + boff[n]);
                if (HBL) blf[n] = *(const bf16x8*)(lds + bb + OBL + boff[n]);
            }
            if (PRIO) __builtin_amdgcn_s_setprio(1);
            #pragma unroll
            for (int m = 0; m < 4; m++)
                #pragma unroll
                for (int n = 0; n < 4; n++) {
                    acc[m][n] = __builtin_amdgcn_mfma_f32_16x16x32_bf16(ah[m], bhf[n], acc[m][n], 0, 0, 0);
                    if (HAL)
                        acc[m][n] = __builtin_amdgcn_mfma_f32_16x16x32_bf16(al[m], bhf[n], acc[m][n], 0, 0, 0);
                    if (HBL)
                        acc[m][n] = __builtin_amdgcn_mfma_f32_16x16x32_bf16(ah[m], blf[n], acc[m][n], 0, 0, 0);
                }
            if (PRIO) __builtin_amdgcn_s_setprio(0);
        }
        asm volatile("s_waitcnt lgkmcnt(0)" ::: "memory");
        __builtin_amdgcn_sched_barrier(0);
        __builtin_amdgcn_s_barrier();
        if (it + 2 < nt) {
            STAGE_GL((it + 2) << 5, bb);
            waitvm<NLOADS>();
            __builtin_amdgcn_s_barrier();
        } else if (it + 1 < nt) {
            waitvm<0>();
            __builtin_amdgcn_s_barrier();
        }
    }

    // epilogue: C/D layout col=lane&15, row=(lane>>4)*4+reg
    #pragma unroll
    for (int m = 0; m < 4; m++) {
        #pragma unroll
        for (int n = 0; n < 4; n++) {
            f32x4 v = acc[m][n];
            int rl0 = wr*64 + m*16 + (lane >> 4)*4;
            int col = n0 + wc*64 + n*16 + l15;
            #pragma unroll
            for (int j = 0; j < 4; j++) {
                float x = v[j];
                int rl = rl0 + j;
                if (EP == EP_RANK) {
                    int s = stok[slot0 + rl];
                    if (s >= 0) {
                        int tt = s & 4095;
                        float ww = sw[slot0 + rl];
                        float* dst = (s & 4096) ? Cb : Ca;
                        dst[(size_t)tt * N + col] = ww * x;
                    }
                } else if (EP == EP_DUAL) {
                    int r = m0 + rl;
                    float* dst = kz ? Cb : Ca;
                    dst[(size_t)r * N + col] = x;
                } else { // EP_FINAL
                    int r = m0 + rl;
                    x += bias[r];
                    int b = col >> 11, s = col & (S_-1);
                    Ca[(((size_t)(b*CLASSES_ + r)) << 11) + s] = x;
                }
            }
        }
    }
#undef STAGE_GL
}

// ---------------- chunked cumsum over Oa+Ob ----------------
#define SC_ 128
#define NCH_ (S_/SC_)
__global__ void cum1(const float* __restrict__ Oa, const float* __restrict__ Ob,
                     float* __restrict__ CS)
{
    int blk = blockIdx.x;
    int b = blk / NCH_, ch = blk % NCH_;
    int c = threadIdx.x;
    int s0 = ch * SC_;
    size_t base = ((size_t)(b*S_ + s0)) * (3*F_) + c;
    float sum = 0.f;
    for (int s = 0; s < SC_; s++) {
        size_t idx = base + (size_t)s * (3*F_);
        sum += Oa[idx] + Ob[idx];
    }
    CS[(size_t)blk * F_ + c] = sum;
}
__global__ void cum23(const float* __restrict__ Oa, const float* __restrict__ Ob,
                      const float* __restrict__ CS, float* __restrict__ FP)
{
    int blk = blockIdx.x;
    int b = blk / NCH_, ch = blk % NCH_;
    int c = threadIdx.x;
    float run = 0.f;
    for (int j = 0; j < ch; j++) run += CS[(size_t)(b*NCH_ + j) * F_ + c];
    int s0 = ch * SC_;
    for (int s = s0; s < s0 + SC_; s++) {
        size_t t = (size_t)b * S_ + s;
        size_t ro = t * (3*F_);
        run += Oa[ro + c] + Ob[ro + c];
        float scl = Oa[ro + F_ + c] + Ob[ro + F_ + c];
        float shf = Oa[ro + 2*F_ + c] + Ob[ro + 2*F_ + c];
        FP[t*F_ + c] = run / (float)(s + 1) * scl + shf;
    }
}

// ---------------- fused norm + recurrence ----------------
__global__ __launch_bounds__(256) void normupd_k(const float* __restrict__ FP,
                                                 float* __restrict__ X0, float* __restrict__ X1)
{
    __shared__ float sb[4];
    int t = blockIdx.x;
    const float* row = FP + (size_t)t * F_;
    int tid = threadIdx.x;
    float v0 = row[tid], v1 = row[tid + 256];
    float s = v0 + v1;
    #pragma unroll
    for (int off = 32; off; off >>= 1) s += __shfl_xor(s, off);
    int w = tid >> 6;
    if ((tid & 63) == 0) sb[w] = s;
    __syncthreads();
    float mean = (sb[0] + sb[1] + sb[2] + sb[3]) * (1.0f / F_);
    v0 -= mean; v1 -= mean;
    float q = v0*v0 + v1*v1;
    #pragma unroll
    for (int off = 32; off; off >>= 1) q += __shfl_xor(q, off);
    __syncthreads();
    if ((tid & 63) == 0) sb[w] = q;
    __syncthreads();
    float ss = sb[0] + sb[1] + sb[2] + sb[3];
    float denom = sqrtf(ss) * 0.04419417382415922f + 1e-5f;
    float sc = 0.70710678118654752f / denom;
    float f0 = v0 * sc, f1 = v1 * sc;
    size_t i0 = (size_t)t * F_ + tid, i1 = i0 + 256;
    float a0 = 0.9f * X0[i0] + 0.1f * f0;
    float a1 = 0.9f * X0[i1] + 0.1f * f1;
    X0[i0] = a0; X1[i0] += a0;
    X0[i1] = a1; X1[i1] += a1;
}

__global__ void concat_k(const float* __restrict__ X0, const float* __restrict__ X1,
                         u16* __restrict__ Xh, u16* __restrict__ Xl)
{
    int t = blockIdx.x;
    for (int c = threadIdx.x; c < F_; c += 256) {
        u16 h, l;
        fsplit(X0[(size_t)t*F_ + c], h, l);
        Xh[(size_t)t*(2*F_) + c] = h;      Xl[(size_t)t*(2*F_) + c] = l;
        fsplit(X1[(size_t)t*F_ + c], h, l);
        Xh[(size_t)t*(2*F_) + F_ + c] = h; Xl[(size_t)t*(2*F_) + F_ + c] = l;
    }
}

extern "C" void kernel_launch(void* const* d_in, const int* in_sizes, int n_in,
                              void* d_out, int out_size, void* d_ws, size_t ws_size,
                              hipStream_t stream)
{
    const int*   inp    = (const int*)  d_in[0];
    const float* embed  = (const float*)d_in[1];
    const float* gin_w  = (const float*)d_in[2];
    const float* w_in   = (const float*)d_in[3];
    const float* conv_w = (const float*)d_in[4];
    const float* gout_w = (const float*)d_in[5];
    const float* w_out  = (const float*)d_in[6];
    const float* out_w  = (const float*)d_in[7];
    const float* out_b  = (const float*)d_in[8];
    float* out = (float*)d_out;

    char* w = (char*)d_ws;
    auto alloc = [&](size_t bytes) { char* r = w; w += (bytes + 255) & ~(size_t)255; return r; };
    float* X0    = (float*)alloc((size_t)T_*F_*4);
    float* X1    = (float*)alloc((size_t)T_*F_*4);
    u16*   Hpadh = (u16*)  alloc((size_t)B_*SP_*I_*2);      // pair (reused as OutWl)
    u16*   Hpadl = (u16*)  alloc((size_t)B_*SP_*I_*2);
    u16*   HCh   = (u16*)  alloc((size_t)T_*I_*2);
    u16*   HCl   = (u16*)  alloc((size_t)T_*I_*2);
    float* FP    = (float*)alloc((size_t)T_*F_*4);          // also X1h|X1l during MoE1
    float* CS    = (float*)alloc((size_t)B_*NCH_*F_*4);
    char*  ar1   = alloc((size_t)T_*3*F_*4);                // Ha / Oa / Xcat h,l
    char*  ar2   = alloc((size_t)T_*I_*4);                  // HC0 / OutWh
    char*  altr  = alloc((size_t)T_*3*F_*4);                // Hb / HC1 / Ob
    u16*   Wh    = (u16*)  alloc((size_t)I_*KW_*I_*2);
    u16*   Wl    = (u16*)  alloc((size_t)I_*KW_*I_*2);
    int2*  e2    = (int2*) alloc((size_t)T_*8);
    float2* w2   = (float2*)alloc((size_t)T_*8);
    int*   stok  = (int*)  alloc((size_t)NSLOT_*4);
    float* sw    = (float*)alloc((size_t)NSLOT_*4);
    int*   cnt   = (int*)  alloc(64);
    int4*  s0    = (int4*) alloc((size_t)GMAX_*16);
    int4*  s1    = (int4*) alloc((size_t)GMAX_*16);

    float* Ha  = (float*)ar1;
    float* Oa  = (float*)ar1;
    float* HC0 = (float*)ar2;
    float* Hb  = (float*)altr;
    float* HC1 = (float*)altr;
    float* Ob  = (float*)altr;
    u16*   X1h = (u16*)FP;                 // FP region dead during MoE1 phase
    u16*   X1l = X1h + (size_t)T_*F_;

    embed_k<<<T_, 256, 0, stream>>>(inp, embed, X0, X1);
    hpadzero_k<<<(B_*6*I_)/256, 256, 0, stream>>>(Hpadh, Hpadl);

    for (int d = 0; d < D_; ++d) {
        // ---------- MoE1 (sparse gather, rank-split stores) ----------
        initslot_k<<<(NSLOT_+255)/256, 256, 0, stream>>>(stok, cnt);
        gatev_k<0, F_><<<T_/8, 512, 0, stream>>>(X1, nullptr, gin_w + (size_t)d*F_*E_, e2, w2, cnt);
        schedscat_k<<<1, 256, 0, stream>>>(cnt, e2, w2, s0, s1, 8, stok, sw);
        split_k<<<(T_*F_)/1024, 256, 0, stream>>>(X1, X1h, X1l);
        transp_k<<<dim3(I_/32, F_/32, E_), 256, 0, stream>>>(
            w_in + (size_t)d*E_*F_*I_, Wh, Wl, F_, I_);
        mgemm<A_GATHER2, EP_RANK, 3, 0, 0><<<dim3(I_/128, GMAX_), 256, 0, stream>>>(
            X1h, X1l, Wh, Wl, Ha, Hb, I_, F_, F_, s0, stok, sw, nullptr);
        hsplit_k<<<T_*I_/1024, 256, 0, stream>>>(Ha, Hb, Hpadh, Hpadl);

        // ---------- causal conv (dense, K-split 2, XCD-chunked, setprio) ----------
        convw_k<<<I_, 256, 0, stream>>>(conv_w + (size_t)d*I_*I_*KW_, Wh, Wl);
        mgemm<A_CONV, EP_DUAL, 3, 1, 1><<<dim3(8, 64), 256, 0, stream>>>(
            Hpadh, Hpadl, Wh, Wl, HC0, HC1, I_, (KW_*I_)/2, KW_*I_, nullptr, nullptr, nullptr, nullptr);
        crelu_k<<<T_*I_/1024, 256, 0, stream>>>(HC0, HC1, HCh, HCl);

        // ---------- MoE2 (sparse gather, rank-split stores) ----------
        initslot_k<<<(NSLOT_+255)/256, 256, 0, stream>>>(stok, cnt);
        gatev_k<1, I_><<<T_/8, 512, 0, stream>>>(HC0, HC1, gout_w + (size_t)d*I_*E_, e2, w2, cnt);
        schedscat_k<<<1, 256, 0, stream>>>(cnt, e2, w2, s0, s1, 4, stok, sw);
        for (int c = 0; c < 2; ++c) {
            transp_k<<<dim3((3*F_)/32, I_/32, 4), 256, 0, stream>>>(
                w_out + (size_t)d*E_*I_*(3*F_) + (size_t)c*4*I_*(3*F_), Wh, Wl, I_, 3*F_);
            const int4* sc = (c == 0) ? s0 : s1;
            if (d == 0)
                mgemm<A_GATHER2, EP_RANK, 3, 0, 0><<<dim3((3*F_)/128, GMAX_), 256, 0, stream>>>(
                    HCh, HCl, Wh, Wl, Oa, Ob, 3*F_, I_, I_, sc, stok, sw, nullptr);
            else
                mgemm<A_GATHER2, EP_RANK, 1, 0, 0><<<dim3((3*F_)/128, GMAX_), 256, 0, stream>>>(
                    HCh, HCl, Wh, Wl, Oa, Ob, 3*F_, I_, I_, sc, stok, sw, nullptr);
        }

        cum1<<<B_*NCH_, F_, 0, stream>>>(Oa, Ob, CS);
        cum23<<<B_*NCH_, F_, 0, stream>>>(Oa, Ob, CS, FP);
        normupd_k<<<T_, 256, 0, stream>>>(FP, X0, X1);
    }

    // ---------- final vocab GEMM (2-pass: OWh.Xh + OWh.Xl) ----------
    u16* Xch  = (u16*)ar1;
    u16* Xcl  = (u16*)(ar1 + (size_t)T_*(2*F_)*2);
    u16* OWh  = (u16*)ar2;
    u16* OWl  = Hpadh;   // unused by the 2-pass kernel but valid memory

    concat_k<<<T_, 256, 0, stream>>>(X0, X1, Xch, Xcl);
    split_k<<<(CLASSES_*2*F_)/1024, 256, 0, stream>>>(out_w, OWh, OWl);
    mgemm<A_SPLIT, EP_FINAL, 2, 0, 0><<<dim3(T_/128, CLASSES_/128), 256, 0, stream>>>(
        OWh, OWl, Xch, Xcl, out, nullptr, T_, 2*F_, 2*F_, nullptr, nullptr, nullptr, out_b);
}

// Round 12
// 1415.532 us; speedup vs baseline: 1.1223x; 1.0359x over previous
//
#include <hip/hip_runtime.h>
#include <math.h>

typedef unsigned short u16;
typedef unsigned int   u32;

#define B_ 2
#define S_ 2048
#define F_ 512
#define I_ 1024
#define E_ 8
#define KW_ 7
#define D_ 2
#define CLASSES_ 8192
#define T_ (B_*S_)
#define SP_ (S_+6)
#define NSLOT_ 9216
#define GMAX_ 72

typedef __bf16 bf16x8 __attribute__((ext_vector_type(8)));
typedef float  f32x4  __attribute__((ext_vector_type(4)));

__device__ __forceinline__ u16 f2b(float f) {
    u32 x = __float_as_uint(f);
    return (u16)((x + 0x7fffu + ((x >> 16) & 1u)) >> 16);
}
__device__ __forceinline__ void fsplit(float v, u16& h, u16& l) {
    u16 hh = f2b(v);
    float hv = __uint_as_float(((u32)hh) << 16);
    h = hh;
    l = f2b(v - hv);
}

template<int N> __device__ __forceinline__ void waitvm() {
    asm volatile("s_waitcnt vmcnt(%0)" :: "n"(N) : "memory");
}

#define GLDS16(g, l) __builtin_amdgcn_global_load_lds( \
    (const __attribute__((address_space(1))) u32*)(g), \
    (__attribute__((address_space(3))) u32*)(l), 16, 0, 0)

// ---------------- misc small kernels ----------------
// embed gather + one-time slot/cnt reset (stream-ordered before first gate)
__global__ void embed_k(const int* __restrict__ inp, const float* __restrict__ emb,
                        float* __restrict__ X0, float* __restrict__ X1,
                        int* __restrict__ stok, int* __restrict__ cnt)
{
    int t = blockIdx.x;
    int r = inp[t];
    const float* e = emb + (size_t)r * (2*F_);
    for (int c = threadIdx.x; c < F_; c += 256) {
        X0[(size_t)t*F_ + c] = e[c];
        X1[(size_t)t*F_ + c] = e[F_ + c];
    }
    int gi = blockIdx.x * 256 + threadIdx.x;
    if (gi < NSLOT_) stok[gi] = -1;
    if (gi < E_) cnt[gi] = 0;
}

// vectorized gate + top2: one wave per token, GW transposed in LDS.
// MODE 1: input = relu(X[f] + X2[f])
template<int MODE, int W>
__global__ __launch_bounds__(512) void gatev_k(const float* __restrict__ X,
                                               const float* __restrict__ X2,
                                               const float* __restrict__ GW,
                                               int2* __restrict__ e2, float2* __restrict__ w2,
                                               int* __restrict__ cnt)
{
    __shared__ float gw[W*E_];            // [e][f]
    for (int i = threadIdx.x; i < W*E_; i += 512) {
        int f = i >> 3, e = i & 7;
        gw[e*W + f] = GW[i];
    }
    __syncthreads();
    int wv = threadIdx.x >> 6, l = threadIdx.x & 63;
    int t = blockIdx.x * 8 + wv;
    const float* xr  = X + (size_t)t * W;
    const float* x2r = MODE ? (X2 + (size_t)t * W) : nullptr;
    float a[8];
    #pragma unroll
    for (int e = 0; e < 8; e++) a[e] = 0.f;
    #pragma unroll
    for (int c = 0; c < W/256; c++) {
        int f = c*256 + l*4;
        float4 x = *(const float4*)(xr + f);
        if (MODE) {
            float4 y = *(const float4*)(x2r + f);
            x.x = fmaxf(x.x + y.x, 0.f); x.y = fmaxf(x.y + y.y, 0.f);
            x.z = fmaxf(x.z + y.z, 0.f); x.w = fmaxf(x.w + y.w, 0.f);
        }
        #pragma unroll
        for (int e = 0; e < 8; e++) {
            float4 g = *(const float4*)(gw + e*W + f);
            a[e] += x.x*g.x + x.y*g.y + x.z*g.z + x.w*g.w;
        }
    }
    #pragma unroll
    for (int e = 0; e < 8; e++) {
        #pragma unroll
        for (int off = 32; off; off >>= 1) a[e] += __shfl_xor(a[e], off);
    }
    if (l == 0) {
        float v0 = -3.4e38f, v1 = -3.4e38f; int i0 = 0, i1 = 0;
        #pragma unroll
        for (int k = 0; k < E_; k++) {
            float v = a[k];
            if (v > v0)      { v1 = v0; i1 = i0; v0 = v; i0 = k; }
            else if (v > v1) { v1 = v;  i1 = k; }
        }
        float ex = expf(v1 - v0);
        e2[t] = make_int2(i0, i1);
        w2[t] = make_float2(1.f/(1.f+ex), ex/(1.f+ex));
        atomicAdd(&cnt[i0], 1);
        atomicAdd(&cnt[i1], 1);
    }
}

// fused schedule build + token scatter; one block. stok = t | (rank<<12)
__global__ __launch_bounds__(256) void schedscat_k(const int* __restrict__ cnt,
                                                   const int2* __restrict__ e2,
                                                   const float2* __restrict__ w2,
                                                   int4* __restrict__ s0, int4* __restrict__ s1,
                                                   int split,
                                                   int* __restrict__ stok, float* __restrict__ sw)
{
    __shared__ int lpos[E_];
    int tid = threadIdx.x;
    int nb[E_], slotst[E_], gst[E_];
    int poff = 0, g0 = 0, g1 = 0;
    #pragma unroll
    for (int e = 0; e < E_; e++) {
        int n = (cnt[e] + 127) >> 7;
        nb[e] = n;
        slotst[e] = poff;
        if (e < split) { gst[e] = g0; g0 += n; }
        else           { gst[e] = g1; g1 += n; }
        poff += n << 7;
    }
    if (tid < E_) lpos[tid] = slotst[tid];
    if (tid < GMAX_) {
        int4 en = make_int4(0,0,0,0);
        for (int e = 0; e < split; e++)
            if (tid >= gst[e] && tid < gst[e] + nb[e])
                en = make_int4(slotst[e] + (tid - gst[e])*128, e, 1, 0);
        s0[tid] = en;
    }
    if (split < E_ && tid >= 128 && tid < 128 + GMAX_) {
        int j = tid - 128;
        int4 en = make_int4(0,0,0,0);
        for (int e = split; e < E_; e++)
            if (j >= gst[e] && j < gst[e] + nb[e])
                en = make_int4(slotst[e] + (j - gst[e])*128, e - split, 1, 0);
        s1[j] = en;
    }
    __syncthreads();
    for (int t = tid; t < T_; t += 256) {
        int2 e = e2[t]; float2 w = w2[t];
        int p0 = atomicAdd(&lpos[e.x], 1);
        stok[p0] = t;          sw[p0] = w.x;      // rank 0
        int p1 = atomicAdd(&lpos[e.y], 1);
        stok[p1] = t | 4096;   sw[p1] = w.y;      // rank 1
    }
}

// ---- weight transpose: src fp32 (R x C) per z -> dst bf16 hi/lo [z][C][R] ----
__global__ __launch_bounds__(256) void transp_k(const float* __restrict__ src0,
                                                u16* __restrict__ dh, u16* __restrict__ dl,
                                                int R, int C)
{
    __shared__ float tl[32][33];
    int z = blockIdx.z;
    const float* src = src0 + (size_t)z * R * C;
    size_t dbase = (size_t)z * R * C;
    int c0 = blockIdx.x * 32, r0 = blockIdx.y * 32;
    int tx = threadIdx.x & 31, ty = threadIdx.x >> 5;
    #pragma unroll
    for (int j = 0; j < 32; j += 8)
        tl[ty + j][tx] = src[(size_t)(r0 + ty + j) * C + c0 + tx];
    __syncthreads();
    #pragma unroll
    for (int j = 0; j < 32; j += 8) {
        u16 h, l; fsplit(tl[tx][ty + j], h, l);
        size_t idx = dbase + (size_t)(c0 + ty + j) * R + r0 + tx;
        dh[idx] = h; dl[idx] = l;
    }
}

// ---- conv weight: (o,i,k) fp32 -> bf16 hi/lo [o][kc*I + i] ----
__global__ __launch_bounds__(256) void convw_k(const float* __restrict__ src,
                                               u16* __restrict__ dh, u16* __restrict__ dl)
{
    __shared__ float row[KW_*I_];
    int o = blockIdx.x;
    const float* s = src + (size_t)o * (KW_*I_);
    for (int c = threadIdx.x; c < KW_*I_; c += 256) row[c] = s[c];
    __syncthreads();
    size_t base = (size_t)o * (KW_*I_);
    for (int j = threadIdx.x; j < KW_*I_; j += 256) {
        int kc = j >> 10, i = j & 1023;
        u16 h, l; fsplit(row[i*KW_ + kc], h, l);
        dh[base + j] = h; dl[base + j] = l;
    }
}

// ---- fp32 -> bf16 hi/lo split (X1 per layer) ----
__global__ void split_k(const float* __restrict__ src, u16* __restrict__ dh, u16* __restrict__ dl)
{
    size_t i = ((size_t)blockIdx.x * 256 + threadIdx.x) * 4;
    float4 v = *(const float4*)(src + i);
    ushort4 oh, ol;
    fsplit(v.x, oh.x, ol.x); fsplit(v.y, oh.y, ol.y);
    fsplit(v.z, oh.z, ol.z); fsplit(v.w, oh.w, ol.w);
    *(ushort4*)(dh + i) = oh;
    *(ushort4*)(dl + i) = ol;
}

// ---- fp32 -> bf16 hi only (out_w; final GEMM is 1-pass) ----
__global__ void splith_k(const float* __restrict__ src, u16* __restrict__ dh)
{
    size_t i = ((size_t)blockIdx.x * 256 + threadIdx.x) * 4;
    float4 v = *(const float4*)(src + i);
    ushort4 oh;
    oh.x = f2b(v.x); oh.y = f2b(v.y); oh.z = f2b(v.z); oh.w = f2b(v.w);
    *(ushort4*)(dh + i) = oh;
}

// ---- relu(Ha+Hb) -> split -> padded hi/lo ----
__global__ void hsplit_k(const float* __restrict__ Ha, const float* __restrict__ Hb,
                         u16* __restrict__ ph, u16* __restrict__ pl)
{
    int gid = blockIdx.x*256 + threadIdx.x;
    int eb = gid * 4;
    int t = eb >> 10, c = eb & 1023;
    float4 a = *(const float4*)(Ha + eb);
    float4 b = *(const float4*)(Hb + eb);
    ushort4 hh, ll;
    fsplit(fmaxf(a.x+b.x,0.f), hh.x, ll.x); fsplit(fmaxf(a.y+b.y,0.f), hh.y, ll.y);
    fsplit(fmaxf(a.z+b.z,0.f), hh.z, ll.z); fsplit(fmaxf(a.w+b.w,0.f), hh.w, ll.w);
    size_t row = (size_t)(t >> 11)*SP_ + 6 + (t & (S_-1));
    *(ushort4*)(ph + (row << 10) + c) = hh;
    *(ushort4*)(pl + (row << 10) + c) = ll;
}

// ---- relu(HC0+HC1) -> split (flat) + slot/cnt reset for MoE2 phase ----
__global__ void crelu_k(const float* __restrict__ a0, const float* __restrict__ a1,
                        u16* __restrict__ dh, u16* __restrict__ dl,
                        int* __restrict__ stok, int* __restrict__ cnt)
{
    size_t i = ((size_t)blockIdx.x * 256 + threadIdx.x) * 4;
    float4 a = *(const float4*)(a0 + i);
    float4 b = *(const float4*)(a1 + i);
    ushort4 hh, ll;
    fsplit(fmaxf(a.x+b.x,0.f), hh.x, ll.x); fsplit(fmaxf(a.y+b.y,0.f), hh.y, ll.y);
    fsplit(fmaxf(a.z+b.z,0.f), hh.z, ll.z); fsplit(fmaxf(a.w+b.w,0.f), hh.w, ll.w);
    *(ushort4*)(dh + i) = hh;
    *(ushort4*)(dl + i) = ll;
    int gi = blockIdx.x * 256 + threadIdx.x;
    if (gi < NSLOT_) stok[gi] = -1;
    if (gi < E_) cnt[gi] = 0;
}

__global__ void hpadzero_k(u16* __restrict__ ph, u16* __restrict__ pl)
{
    int idx = blockIdx.x*256 + threadIdx.x;   // B_*6*I_
    int b = idx / (6*I_);
    int rem = idx - b*(6*I_);
    size_t a = ((size_t)b*SP_ + (rem >> 10))*I_ + (rem & 1023);
    ph[a] = 0; pl[a] = 0;
}

// =================== split-bf16 MFMA GEMM, 128x128 tile, BK=32 ===================
// Counted-vmcnt 2-deep pipeline; per-wave 64x64 output.
// SWZ=1 (conv only): balanced 2D XCD chunk, grid must be (8,64).
// PRIO=1 (conv only): s_setprio around the MFMA cluster.
enum { A_SPLIT=0, A_CONV=1, A_GATHER2=2 };
enum { EP_RANK=0, EP_DUAL=1, EP_FINAL=2 };

#define SBSZ(Pv) ((((Pv)==3)?16384:8192) + 8192*(((Pv)>=2)?2:1))

template<int AM, int EP, int PASSES, int SWZ, int PRIO>
__global__ __launch_bounds__(256, ((2*SBSZ(PASSES)) <= 32768) ? 4 : (((2*SBSZ(PASSES)) <= 49152) ? 3 : 2))
void mgemm(const void* __restrict__ A1, const void* __restrict__ A2,
           const u16* __restrict__ Bh, const u16* __restrict__ Bl,
           float* __restrict__ Ca, float* __restrict__ Cb,
           int N, int Kd, int ldb,
           const int4* __restrict__ sched, const int* __restrict__ stok,
           const float* __restrict__ sw, const float* __restrict__ bias)
{
    constexpr bool HAL = (PASSES==3);
    constexpr bool HBL = (PASSES>=2);
    constexpr int OAL  = 8192;
    constexpr int OBH  = (HAL ? 16384 : 8192);
    constexpr int OBL  = OBH + 8192;
    constexpr int SB   = OBH + 8192*(HBL ? 2 : 1);
    constexpr int NLOADS = 2*(HBL ? 2 : 1) + 2*(HAL ? 2 : 1);
    __shared__ uint4 ldsv[2*SB/16];
    char* lds = (char*)ldsv;

    const int tid  = threadIdx.x;
    const int lane = tid & 63, wid = tid >> 6;
    int n0 = blockIdx.x * 128;

    int slot0 = 0, m0 = 0, koff = 0, kz = 0;
    const u16 *bhb = Bh, *blb = Bl;
    if (AM == A_GATHER2) {
        int4 sc = sched[blockIdx.y];
        if (!sc.z) return;
        slot0 = sc.x;
        size_t wo = (size_t)sc.y * N * ldb;
        bhb = Bh + wo; blb = Bl + wo;
    } else if (AM == A_CONV) {
        if (SWZ == 1) {
            int fid = blockIdx.y * 8 + blockIdx.x;
            int xcd = fid & 7, k = fid >> 3;
            int mp = (xcd >> 1) * 8 + (k >> 3);          // 0..31
            int np = (xcd & 1) * 8 + (k & 7);            // 0..15
            m0 = mp * 128;
            kz = np >> 3;
            koff = kz * Kd;
            n0 = (np & 7) * 128;
        } else {
            m0 = (blockIdx.y & 31) * 128;
            kz = blockIdx.y >> 5;
            koff = kz * Kd;
        }
    } else {
        m0 = blockIdx.y * 128;
    }

    // staging geometry
    int srow[2], klog[2];
    #pragma unroll
    for (int c = 0; c < 2; c++) {
        int row = (tid >> 2) + c*64;
        srow[c] = row;
        klog[c] = ((tid & 3) ^ ((row >> 1) & 3)) << 3;
    }

    const u16 *bgh[2], *bgl[2];
    #pragma unroll
    for (int c = 0; c < 2; c++) {
        size_t off = (size_t)(n0 + srow[c]) * ldb + koff + klog[c];
        bgh[c] = bhb + off;
        bgl[c] = blb + off;
    }

    const u16 *a1p[2], *a2p[2];
    #pragma unroll
    for (int c = 0; c < 2; c++) {
        if (AM == A_SPLIT) {
            size_t off = (size_t)(m0 + srow[c]) * Kd + klog[c];
            a1p[c] = (const u16*)A1 + off;
            a2p[c] = (const u16*)A2 + off;
        } else if (AM == A_CONV) {
            int t = m0 + srow[c];
            size_t rb = (((size_t)(t >> 11)*SP_ + (t & (S_-1))) << 10) + koff + klog[c];
            a1p[c] = (const u16*)A1 + rb;
            a2p[c] = (const u16*)A2 + rb;
        } else { // A_GATHER2
            int s = stok[slot0 + srow[c]];
            int tk = (s < 0) ? 0 : (s & 4095);
            size_t off = (size_t)tk * Kd + klog[c];
            a1p[c] = (const u16*)A1 + off;
            a2p[c] = (const u16*)A2 + off;
        }
    }

    // fragment read offsets (swizzle matches staging); 4 waves as 2x2 of 64x64
    const int wr = wid >> 1, wc = wid & 1;
    const int l15 = lane & 15, kq = lane >> 4;
    int aoff[4], boff[4];
    #pragma unroll
    for (int m = 0; m < 4; m++) {
        int ra = wr*64 + m*16 + l15;
        aoff[m] = ra*64 + ((kq ^ ((ra >> 1) & 3)) << 4);
    }
    #pragma unroll
    for (int n = 0; n < 4; n++) {
        int rb = wc*64 + n*16 + l15;
        boff[n] = rb*64 + ((kq ^ ((rb >> 1) & 3)) << 4);
    }

    f32x4 acc[4][4];
    #pragma unroll
    for (int m = 0; m < 4; m++)
        #pragma unroll
        for (int n = 0; n < 4; n++) acc[m][n] = {0.f,0.f,0.f,0.f};

    const int nt = Kd >> 5;

#define STAGE_GL(K0, BB)                                                          \
    {                                                                             \
        _Pragma("unroll")                                                         \
        for (int c = 0; c < 2; c++) {                                             \
            GLDS16(bgh[c] + (K0), lds + (BB) + OBH + c*4096 + (wid<<10));         \
            if (HBL)                                                              \
                GLDS16(bgl[c] + (K0), lds + (BB) + OBL + c*4096 + (wid<<10));     \
        }                                                                         \
        _Pragma("unroll")                                                         \
        for (int c = 0; c < 2; c++) {                                             \
            GLDS16(a1p[c] + (K0), lds + (BB) + c*4096 + (wid<<10));               \
            if (HAL)                                                              \
                GLDS16(a2p[c] + (K0), lds + (BB) + OAL + c*4096 + (wid<<10));     \
        }                                                                         \
    }

    // prologue: 2-deep prefetch
    STAGE_GL(0, 0);
    STAGE_GL(32, SB);
    waitvm<NLOADS>();
    __builtin_amdgcn_s_barrier();

    for (int it = 0; it < nt; ++it) {
        const int bb = (it & 1) * SB;
        {
            bf16x8 ah[4], al[4], bhf[4], blf[4];
            #pragma unroll
            for (int m = 0; m < 4; m++) {
                ah[m] = *(const bf16x8*)(lds + bb + aoff[m]);
                if (HAL) al[m] = *(const bf16x8*)(lds + bb + OAL + aoff[m]);
            }
            #pragma unroll
            for (int n = 0; n < 4; n++) {
                bhf[n] = *(const bf16x8*)(lds + bb + OBH + boff[n]);
                if (HBL) blf[n] = *(const bf16x8*)(lds + bb + OBL + boff[n]);
            }
            if (PRIO) __builtin_amdgcn_s_setprio(1);
            #pragma unroll
            for (int m = 0; m < 4; m++)
                #pragma unroll
                for (int n = 0; n < 4; n++) {
                    acc[m][n] = __builtin_amdgcn_mfma_f32_16x16x32_bf16(ah[m], bhf[n], acc[m][n], 0, 0, 0);
                    if (HAL)
                        acc[m][n] = __builtin_amdgcn_mfma_f32_16x16x32_bf16(al[m], bhf[n], acc[m][n], 0, 0, 0);
                    if (HBL)
                        acc[m][n] = __builtin_amdgcn_mfma_f32_16x16x32_bf16(ah[m], blf[n], acc[m][n], 0, 0, 0);
                }
            if (PRIO) __builtin_amdgcn_s_setprio(0);
        }
        asm volatile("s_waitcnt lgkmcnt(0)" ::: "memory");
        __builtin_amdgcn_sched_barrier(0);
        __builtin_amdgcn_s_barrier();
        if (it + 2 < nt) {
            STAGE_GL((it + 2) << 5, bb);
            waitvm<NLOADS>();
            __builtin_amdgcn_s_barrier();
        } else if (it + 1 < nt) {
            waitvm<0>();
            __builtin_amdgcn_s_barrier();
        }
    }

    // epilogue: C/D layout col=lane&15, row=(lane>>4)*4+reg
    #pragma unroll
    for (int m = 0; m < 4; m++) {
        #pragma unroll
        for (int n = 0; n < 4; n++) {
            f32x4 v = acc[m][n];
            int rl0 = wr*64 + m*16 + (lane >> 4)*4;
            int col = n0 + wc*64 + n*16 + l15;
            #pragma unroll
            for (int j = 0; j < 4; j++) {
                float x = v[j];
                int rl = rl0 + j;
                if (EP == EP_RANK) {
                    int s = stok[slot0 + rl];
                    if (s >= 0) {
                        int tt = s & 4095;
                        float ww = sw[slot0 + rl];
                        float* dst = (s & 4096) ? Cb : Ca;
                        dst[(size_t)tt * N + col] = ww * x;
                    }
                } else if (EP == EP_DUAL) {
                    int r = m0 + rl;
                    float* dst = kz ? Cb : Ca;
                    dst[(size_t)r * N + col] = x;
                } else { // EP_FINAL
                    int r = m0 + rl;
                    x += bias[r];
                    int b = col >> 11, s = col & (S_-1);
                    Ca[(((size_t)(b*CLASSES_ + r)) << 11) + s] = x;
                }
            }
        }
    }
#undef STAGE_GL
}

// ---------------- chunked cumsum over Oa+Ob ----------------
#define SC_ 128
#define NCH_ (S_/SC_)
__global__ void cum1(const float* __restrict__ Oa, const float* __restrict__ Ob,
                     float* __restrict__ CS)
{
    int blk = blockIdx.x;
    int b = blk / NCH_, ch = blk % NCH_;
    int c = threadIdx.x;
    int s0 = ch * SC_;
    size_t base = ((size_t)(b*S_ + s0)) * (3*F_) + c;
    float sum = 0.f;
    for (int s = 0; s < SC_; s++) {
        size_t idx = base + (size_t)s * (3*F_);
        sum += Oa[idx] + Ob[idx];
    }
    CS[(size_t)blk * F_ + c] = sum;
}
__global__ void cum23(const float* __restrict__ Oa, const float* __restrict__ Ob,
                      const float* __restrict__ CS, float* __restrict__ FP)
{
    int blk = blockIdx.x;
    int b = blk / NCH_, ch = blk % NCH_;
    int c = threadIdx.x;
    float run = 0.f;
    for (int j = 0; j < ch; j++) run += CS[(size_t)(b*NCH_ + j) * F_ + c];
    int s0 = ch * SC_;
    for (int s = s0; s < s0 + SC_; s++) {
        size_t t = (size_t)b * S_ + s;
        size_t ro = t * (3*F_);
        run += Oa[ro + c] + Ob[ro + c];
        float scl = Oa[ro + F_ + c] + Ob[ro + F_ + c];
        float shf = Oa[ro + 2*F_ + c] + Ob[ro + 2*F_ + c];
        FP[t*F_ + c] = run / (float)(s + 1) * scl + shf;
    }
}

// ---------------- fused norm + recurrence (+ Xcat-hi on last layer, + slot reset) ----------------
__global__ __launch_bounds__(256) void normupd_k(const float* __restrict__ FP,
                                                 float* __restrict__ X0, float* __restrict__ X1,
                                                 u16* __restrict__ xch,
                                                 int* __restrict__ stok, int* __restrict__ cnt)
{
    __shared__ float sb[4];
    int t = blockIdx.x;
    const float* row = FP + (size_t)t * F_;
    int tid = threadIdx.x;
    float v0 = row[tid], v1 = row[tid + 256];
    float s = v0 + v1;
    #pragma unroll
    for (int off = 32; off; off >>= 1) s += __shfl_xor(s, off);
    int w = tid >> 6;
    if ((tid & 63) == 0) sb[w] = s;
    __syncthreads();
    float mean = (sb[0] + sb[1] + sb[2] + sb[3]) * (1.0f / F_);
    v0 -= mean; v1 -= mean;
    float q = v0*v0 + v1*v1;
    #pragma unroll
    for (int off = 32; off; off >>= 1) q += __shfl_xor(q, off);
    __syncthreads();
    if ((tid & 63) == 0) sb[w] = q;
    __syncthreads();
    float ss = sb[0] + sb[1] + sb[2] + sb[3];
    float denom = sqrtf(ss) * 0.04419417382415922f + 1e-5f;
    float sc = 0.70710678118654752f / denom;
    float f0 = v0 * sc, f1 = v1 * sc;
    size_t i0 = (size_t)t * F_ + tid, i1 = i0 + 256;
    float a0 = 0.9f * X0[i0] + 0.1f * f0;
    float a1 = 0.9f * X0[i1] + 0.1f * f1;
    float x1n0 = X1[i0] + a0;
    float x1n1 = X1[i1] + a1;
    X0[i0] = a0; X1[i0] = x1n0;
    X0[i1] = a1; X1[i1] = x1n1;
    if (xch) {   // last layer: write Xcat-hi = [X0_new | X1_new] in bf16
        size_t xb = (size_t)t * (2*F_);
        xch[xb + tid]            = f2b(a0);
        xch[xb + tid + 256]      = f2b(a1);
        xch[xb + F_ + tid]       = f2b(x1n0);
        xch[xb + F_ + tid + 256] = f2b(x1n1);
    }
    int gi = blockIdx.x * 256 + tid;
    if (gi < NSLOT_) stok[gi] = -1;
    if (gi < E_) cnt[gi] = 0;
}

extern "C" void kernel_launch(void* const* d_in, const int* in_sizes, int n_in,
                              void* d_out, int out_size, void* d_ws, size_t ws_size,
                              hipStream_t stream)
{
    const int*   inp    = (const int*)  d_in[0];
    const float* embed  = (const float*)d_in[1];
    const float* gin_w  = (const float*)d_in[2];
    const float* w_in   = (const float*)d_in[3];
    const float* conv_w = (const float*)d_in[4];
    const float* gout_w = (const float*)d_in[5];
    const float* w_out  = (const float*)d_in[6];
    const float* out_w  = (const float*)d_in[7];
    const float* out_b  = (const float*)d_in[8];
    float* out = (float*)d_out;

    char* w = (char*)d_ws;
    auto alloc = [&](size_t bytes) { char* r = w; w += (bytes + 255) & ~(size_t)255; return r; };
    float* X0    = (float*)alloc((size_t)T_*F_*4);
    float* X1    = (float*)alloc((size_t)T_*F_*4);
    u16*   Hpadh = (u16*)  alloc((size_t)B_*SP_*I_*2);
    u16*   Hpadl = (u16*)  alloc((size_t)B_*SP_*I_*2);
    u16*   HCh   = (u16*)  alloc((size_t)T_*I_*2);
    u16*   HCl   = (u16*)  alloc((size_t)T_*I_*2);
    float* FP    = (float*)alloc((size_t)T_*F_*4);          // also X1h|X1l during MoE1
    float* CS    = (float*)alloc((size_t)B_*NCH_*F_*4);
    char*  ar1   = alloc((size_t)T_*3*F_*4);                // Ha / Oa / Xcat-hi
    char*  ar2   = alloc((size_t)T_*I_*4);                  // HC0 / OutWh
    char*  altr  = alloc((size_t)T_*3*F_*4);                // Hb / HC1 / Ob
    u16*   Wh    = (u16*)  alloc((size_t)I_*KW_*I_*2);
    u16*   Wl    = (u16*)  alloc((size_t)I_*KW_*I_*2);
    int2*  e2    = (int2*) alloc((size_t)T_*8);
    float2* w2   = (float2*)alloc((size_t)T_*8);
    int*   stok  = (int*)  alloc((size_t)NSLOT_*4);
    float* sw    = (float*)alloc((size_t)NSLOT_*4);
    int*   cnt   = (int*)  alloc(64);
    int4*  s0    = (int4*) alloc((size_t)GMAX_*16);
    int4*  s1    = (int4*) alloc((size_t)GMAX_*16);

    float* Ha  = (float*)ar1;
    float* Oa  = (float*)ar1;
    float* HC0 = (float*)ar2;
    float* Hb  = (float*)altr;
    float* HC1 = (float*)altr;
    float* Ob  = (float*)altr;
    u16*   X1h = (u16*)FP;                 // FP region dead during MoE1 phase
    u16*   X1l = X1h + (size_t)T_*F_;
    u16*   Xch = (u16*)ar1;                // last-layer Xcat-hi (written by normupd)
    u16*   OWh = (u16*)ar2;

    embed_k<<<T_, 256, 0, stream>>>(inp, embed, X0, X1, stok, cnt);
    hpadzero_k<<<(B_*6*I_)/256, 256, 0, stream>>>(Hpadh, Hpadl);

    for (int d = 0; d < D_; ++d) {
        // ---------- MoE1 (sparse gather, rank-split stores) ----------
        gatev_k<0, F_><<<T_/8, 512, 0, stream>>>(X1, nullptr, gin_w + (size_t)d*F_*E_, e2, w2, cnt);
        schedscat_k<<<1, 256, 0, stream>>>(cnt, e2, w2, s0, s1, 8, stok, sw);
        split_k<<<(T_*F_)/1024, 256, 0, stream>>>(X1, X1h, X1l);
        transp_k<<<dim3(I_/32, F_/32, E_), 256, 0, stream>>>(
            w_in + (size_t)d*E_*F_*I_, Wh, Wl, F_, I_);
        mgemm<A_GATHER2, EP_RANK, 3, 0, 0><<<dim3(I_/128, GMAX_), 256, 0, stream>>>(
            X1h, X1l, Wh, Wl, Ha, Hb, I_, F_, F_, s0, stok, sw, nullptr);
        hsplit_k<<<T_*I_/1024, 256, 0, stream>>>(Ha, Hb, Hpadh, Hpadl);

        // ---------- causal conv (dense, K-split 2, XCD-chunked, setprio) ----------
        convw_k<<<I_, 256, 0, stream>>>(conv_w + (size_t)d*I_*I_*KW_, Wh, Wl);
        mgemm<A_CONV, EP_DUAL, 3, 1, 1><<<dim3(8, 64), 256, 0, stream>>>(
            Hpadh, Hpadl, Wh, Wl, HC0, HC1, I_, (KW_*I_)/2, KW_*I_, nullptr, nullptr, nullptr, nullptr);
        crelu_k<<<T_*I_/1024, 256, 0, stream>>>(HC0, HC1, HCh, HCl, stok, cnt);

        // ---------- MoE2 (sparse gather, rank-split stores) ----------
        gatev_k<1, I_><<<T_/8, 512, 0, stream>>>(HC0, HC1, gout_w + (size_t)d*I_*E_, e2, w2, cnt);
        schedscat_k<<<1, 256, 0, stream>>>(cnt, e2, w2, s0, s1, 4, stok, sw);
        for (int c = 0; c < 2; ++c) {
            transp_k<<<dim3((3*F_)/32, I_/32, 4), 256, 0, stream>>>(
                w_out + (size_t)d*E_*I_*(3*F_) + (size_t)c*4*I_*(3*F_), Wh, Wl, I_, 3*F_);
            const int4* sc = (c == 0) ? s0 : s1;
            if (d == 0)
                mgemm<A_GATHER2, EP_RANK, 3, 0, 0><<<dim3((3*F_)/128, GMAX_), 256, 0, stream>>>(
                    HCh, HCl, Wh, Wl, Oa, Ob, 3*F_, I_, I_, sc, stok, sw, nullptr);
            else
                mgemm<A_GATHER2, EP_RANK, 1, 0, 0><<<dim3((3*F_)/128, GMAX_), 256, 0, stream>>>(
                    HCh, HCl, Wh, Wl, Oa, Ob, 3*F_, I_, I_, sc, stok, sw, nullptr);
        }

        cum1<<<B_*NCH_, F_, 0, stream>>>(Oa, Ob, CS);
        cum23<<<B_*NCH_, F_, 0, stream>>>(Oa, Ob, CS, FP);
        normupd_k<<<T_, 256, 0, stream>>>(FP, X0, X1,
                                          (d == D_-1) ? Xch : (u16*)nullptr, stok, cnt);
    }

    // ---------- final vocab GEMM (1-pass: OWh.Xh) ----------
    splith_k<<<(CLASSES_*2*F_)/1024, 256, 0, stream>>>(out_w, OWh);
    mgemm<A_SPLIT, EP_FINAL, 1, 0, 0><<<dim3(T_/128, CLASSES_/128), 256, 0, stream>>>(
        OWh, OWh, Xch, Xch, out, nullptr, T_, 2*F_, 2*F_, nullptr, nullptr, nullptr, out_b);
}

// Round 13
// 1392.475 us; speedup vs baseline: 1.1409x; 1.0166x over previous
//
#include <hip/hip_runtime.h>
#include <math.h>

typedef unsigned short u16;
typedef unsigned int   u32;

#define B_ 2
#define S_ 2048
#define F_ 512
#define I_ 1024
#define E_ 8
#define KW_ 7
#define D_ 2
#define CLASSES_ 8192
#define T_ (B_*S_)
#define SP_ (S_+6)
#define NSLOT_ 9216
#define GMAX_ 72

typedef __bf16 bf16x8 __attribute__((ext_vector_type(8)));
typedef float  f32x4  __attribute__((ext_vector_type(4)));

__device__ __forceinline__ u16 f2b(float f) {
    u32 x = __float_as_uint(f);
    return (u16)((x + 0x7fffu + ((x >> 16) & 1u)) >> 16);
}
__device__ __forceinline__ float b2f(u16 h) {
    return __uint_as_float(((u32)h) << 16);
}
__device__ __forceinline__ void fsplit(float v, u16& h, u16& l) {
    u16 hh = f2b(v);
    float hv = __uint_as_float(((u32)hh) << 16);
    h = hh;
    l = f2b(v - hv);
}

template<int N> __device__ __forceinline__ void waitvm() {
    asm volatile("s_waitcnt vmcnt(%0)" :: "n"(N) : "memory");
}

#define GLDS16(g, l) __builtin_amdgcn_global_load_lds( \
    (const __attribute__((address_space(1))) u32*)(g), \
    (__attribute__((address_space(3))) u32*)(l), 16, 0, 0)

// ---------------- misc small kernels ----------------
// embed gather (X1 stored as bf16 hi/lo) + one-time slot/cnt reset
__global__ void embed_k(const int* __restrict__ inp, const float* __restrict__ emb,
                        float* __restrict__ X0, u16* __restrict__ X1h, u16* __restrict__ X1l,
                        int* __restrict__ stok, int* __restrict__ cnt)
{
    int t = blockIdx.x;
    int r = inp[t];
    const float* e = emb + (size_t)r * (2*F_);
    for (int c = threadIdx.x; c < F_; c += 256) {
        X0[(size_t)t*F_ + c] = e[c];
        u16 h, l; fsplit(e[F_ + c], h, l);
        X1h[(size_t)t*F_ + c] = h;
        X1l[(size_t)t*F_ + c] = l;
    }
    int gi = blockIdx.x * 256 + threadIdx.x;
    if (gi < NSLOT_) stok[gi] = -1;
    if (gi < E_) cnt[gi] = 0;
}

// gate1 + top2 from bf16 hi/lo X1: one wave per token, GW transposed in LDS
__global__ __launch_bounds__(512) void gatebf_k(const u16* __restrict__ Xh,
                                                const u16* __restrict__ Xl,
                                                const float* __restrict__ GW,
                                                int2* __restrict__ e2, float2* __restrict__ w2,
                                                int* __restrict__ cnt)
{
    __shared__ float gw[F_*E_];           // [e][f]
    for (int i = threadIdx.x; i < F_*E_; i += 512) {
        int f = i >> 3, e = i & 7;
        gw[e*F_ + f] = GW[i];
    }
    __syncthreads();
    int wv = threadIdx.x >> 6, l = threadIdx.x & 63;
    int t = blockIdx.x * 8 + wv;
    const u16* xh = Xh + (size_t)t * F_;
    const u16* xl = Xl + (size_t)t * F_;
    float a[8];
    #pragma unroll
    for (int e = 0; e < 8; e++) a[e] = 0.f;
    #pragma unroll
    for (int c = 0; c < F_/256; c++) {
        int f = c*256 + l*4;
        ushort4 h4 = *(const ushort4*)(xh + f);
        ushort4 l4 = *(const ushort4*)(xl + f);
        float4 x;
        x.x = b2f(h4.x) + b2f(l4.x); x.y = b2f(h4.y) + b2f(l4.y);
        x.z = b2f(h4.z) + b2f(l4.z); x.w = b2f(h4.w) + b2f(l4.w);
        #pragma unroll
        for (int e = 0; e < 8; e++) {
            float4 g = *(const float4*)(gw + e*F_ + f);
            a[e] += x.x*g.x + x.y*g.y + x.z*g.z + x.w*g.w;
        }
    }
    #pragma unroll
    for (int e = 0; e < 8; e++) {
        #pragma unroll
        for (int off = 32; off; off >>= 1) a[e] += __shfl_xor(a[e], off);
    }
    if (l == 0) {
        float v0 = -3.4e38f, v1 = -3.4e38f; int i0 = 0, i1 = 0;
        #pragma unroll
        for (int k = 0; k < E_; k++) {
            float v = a[k];
            if (v > v0)      { v1 = v0; i1 = i0; v0 = v; i0 = k; }
            else if (v > v1) { v1 = v;  i1 = k; }
        }
        float ex = expf(v1 - v0);
        e2[t] = make_int2(i0, i1);
        w2[t] = make_float2(1.f/(1.f+ex), ex/(1.f+ex));
        atomicAdd(&cnt[i0], 1);
        atomicAdd(&cnt[i1], 1);
    }
}

// fused gate2 + relu(HC0+HC1) hi/lo split: one wave per token
__global__ __launch_bounds__(512) void gatecrelu_k(const float* __restrict__ A0,
                                                   const float* __restrict__ A1v,
                                                   const float* __restrict__ GW,
                                                   u16* __restrict__ Hh, u16* __restrict__ Hl,
                                                   int2* __restrict__ e2, float2* __restrict__ w2,
                                                   int* __restrict__ cnt)
{
    __shared__ float gw[I_*E_];           // [e][f]
    for (int i = threadIdx.x; i < I_*E_; i += 512) {
        int f = i >> 3, e = i & 7;
        gw[e*I_ + f] = GW[i];
    }
    __syncthreads();
    int wv = threadIdx.x >> 6, l = threadIdx.x & 63;
    int t = blockIdx.x * 8 + wv;
    const float* xr  = A0 + (size_t)t * I_;
    const float* x2r = A1v + (size_t)t * I_;
    float a[8];
    #pragma unroll
    for (int e = 0; e < 8; e++) a[e] = 0.f;
    #pragma unroll
    for (int c = 0; c < I_/256; c++) {
        int f = c*256 + l*4;
        float4 x = *(const float4*)(xr + f);
        float4 y = *(const float4*)(x2r + f);
        x.x = fmaxf(x.x + y.x, 0.f); x.y = fmaxf(x.y + y.y, 0.f);
        x.z = fmaxf(x.z + y.z, 0.f); x.w = fmaxf(x.w + y.w, 0.f);
        ushort4 oh, ol;
        fsplit(x.x, oh.x, ol.x); fsplit(x.y, oh.y, ol.y);
        fsplit(x.z, oh.z, ol.z); fsplit(x.w, oh.w, ol.w);
        *(ushort4*)(Hh + (size_t)t*I_ + f) = oh;
        *(ushort4*)(Hl + (size_t)t*I_ + f) = ol;
        #pragma unroll
        for (int e = 0; e < 8; e++) {
            float4 g = *(const float4*)(gw + e*I_ + f);
            a[e] += x.x*g.x + x.y*g.y + x.z*g.z + x.w*g.w;
        }
    }
    #pragma unroll
    for (int e = 0; e < 8; e++) {
        #pragma unroll
        for (int off = 32; off; off >>= 1) a[e] += __shfl_xor(a[e], off);
    }
    if (l == 0) {
        float v0 = -3.4e38f, v1 = -3.4e38f; int i0 = 0, i1 = 0;
        #pragma unroll
        for (int k = 0; k < E_; k++) {
            float v = a[k];
            if (v > v0)      { v1 = v0; i1 = i0; v0 = v; i0 = k; }
            else if (v > v1) { v1 = v;  i1 = k; }
        }
        float ex = expf(v1 - v0);
        e2[t] = make_int2(i0, i1);
        w2[t] = make_float2(1.f/(1.f+ex), ex/(1.f+ex));
        atomicAdd(&cnt[i0], 1);
        atomicAdd(&cnt[i1], 1);
    }
}

// fused schedule build + token scatter; one block. stok = t | (rank<<12)
__global__ __launch_bounds__(256) void schedscat_k(const int* __restrict__ cnt,
                                                   const int2* __restrict__ e2,
                                                   const float2* __restrict__ w2,
                                                   int4* __restrict__ s0, int4* __restrict__ s1,
                                                   int split,
                                                   int* __restrict__ stok, float* __restrict__ sw)
{
    __shared__ int lpos[E_];
    int tid = threadIdx.x;
    int nb[E_], slotst[E_], gst[E_];
    int poff = 0, g0 = 0, g1 = 0;
    #pragma unroll
    for (int e = 0; e < E_; e++) {
        int n = (cnt[e] + 127) >> 7;
        nb[e] = n;
        slotst[e] = poff;
        if (e < split) { gst[e] = g0; g0 += n; }
        else           { gst[e] = g1; g1 += n; }
        poff += n << 7;
    }
    if (tid < E_) lpos[tid] = slotst[tid];
    if (tid < GMAX_) {
        int4 en = make_int4(0,0,0,0);
        for (int e = 0; e < split; e++)
            if (tid >= gst[e] && tid < gst[e] + nb[e])
                en = make_int4(slotst[e] + (tid - gst[e])*128, e, 1, 0);
        s0[tid] = en;
    }
    if (split < E_ && tid >= 128 && tid < 128 + GMAX_) {
        int j = tid - 128;
        int4 en = make_int4(0,0,0,0);
        for (int e = split; e < E_; e++)
            if (j >= gst[e] && j < gst[e] + nb[e])
                en = make_int4(slotst[e] + (j - gst[e])*128, e - split, 1, 0);
        s1[j] = en;
    }
    __syncthreads();
    for (int t = tid; t < T_; t += 256) {
        int2 e = e2[t]; float2 w = w2[t];
        int p0 = atomicAdd(&lpos[e.x], 1);
        stok[p0] = t;          sw[p0] = w.x;      // rank 0
        int p1 = atomicAdd(&lpos[e.y], 1);
        stok[p1] = t | 4096;   sw[p1] = w.y;      // rank 1
    }
}

// ---- weight transpose: src fp32 (R x C) per z -> dst bf16 hi/lo [z][C][R] ----
__global__ __launch_bounds__(256) void transp_k(const float* __restrict__ src0,
                                                u16* __restrict__ dh, u16* __restrict__ dl,
                                                int R, int C)
{
    __shared__ float tl[32][33];
    int z = blockIdx.z;
    const float* src = src0 + (size_t)z * R * C;
    size_t dbase = (size_t)z * R * C;
    int c0 = blockIdx.x * 32, r0 = blockIdx.y * 32;
    int tx = threadIdx.x & 31, ty = threadIdx.x >> 5;
    #pragma unroll
    for (int j = 0; j < 32; j += 8)
        tl[ty + j][tx] = src[(size_t)(r0 + ty + j) * C + c0 + tx];
    __syncthreads();
    #pragma unroll
    for (int j = 0; j < 32; j += 8) {
        u16 h, l; fsplit(tl[tx][ty + j], h, l);
        size_t idx = dbase + (size_t)(c0 + ty + j) * R + r0 + tx;
        dh[idx] = h; dl[idx] = l;
    }
}

// ---- conv weight: (o,i,k) fp32 -> bf16 hi/lo [o][kc*I + i] ----
__global__ __launch_bounds__(256) void convw_k(const float* __restrict__ src,
                                               u16* __restrict__ dh, u16* __restrict__ dl)
{
    __shared__ float row[KW_*I_];
    int o = blockIdx.x;
    const float* s = src + (size_t)o * (KW_*I_);
    for (int c = threadIdx.x; c < KW_*I_; c += 256) row[c] = s[c];
    __syncthreads();
    size_t base = (size_t)o * (KW_*I_);
    for (int j = threadIdx.x; j < KW_*I_; j += 256) {
        int kc = j >> 10, i = j & 1023;
        u16 h, l; fsplit(row[i*KW_ + kc], h, l);
        dh[base + j] = h; dl[base + j] = l;
    }
}

// ---- fp32 -> bf16 hi only (out_w; final GEMM is 1-pass) ----
__global__ void splith_k(const float* __restrict__ src, u16* __restrict__ dh)
{
    size_t i = ((size_t)blockIdx.x * 256 + threadIdx.x) * 4;
    float4 v = *(const float4*)(src + i);
    ushort4 oh;
    oh.x = f2b(v.x); oh.y = f2b(v.y); oh.z = f2b(v.z); oh.w = f2b(v.w);
    *(ushort4*)(dh + i) = oh;
}

// ---- relu(Ha+Hb) -> split -> padded hi/lo  (+ slot/cnt reset for MoE2 phase) ----
__global__ void hsplit_k(const float* __restrict__ Ha, const float* __restrict__ Hb,
                         u16* __restrict__ ph, u16* __restrict__ pl,
                         int* __restrict__ stok, int* __restrict__ cnt)
{
    int gid = blockIdx.x*256 + threadIdx.x;
    int eb = gid * 4;
    int t = eb >> 10, c = eb & 1023;
    float4 a = *(const float4*)(Ha + eb);
    float4 b = *(const float4*)(Hb + eb);
    ushort4 hh, ll;
    fsplit(fmaxf(a.x+b.x,0.f), hh.x, ll.x); fsplit(fmaxf(a.y+b.y,0.f), hh.y, ll.y);
    fsplit(fmaxf(a.z+b.z,0.f), hh.z, ll.z); fsplit(fmaxf(a.w+b.w,0.f), hh.w, ll.w);
    size_t row = (size_t)(t >> 11)*SP_ + 6 + (t & (S_-1));
    *(ushort4*)(ph + (row << 10) + c) = hh;
    *(ushort4*)(pl + (row << 10) + c) = ll;
    if (gid < NSLOT_) stok[gid] = -1;
    if (gid < E_) cnt[gid] = 0;
}

__global__ void hpadzero_k(u16* __restrict__ ph, u16* __restrict__ pl)
{
    int idx = blockIdx.x*256 + threadIdx.x;   // B_*6*I_
    int b = idx / (6*I_);
    int rem = idx - b*(6*I_);
    size_t a = ((size_t)b*SP_ + (rem >> 10))*I_ + (rem & 1023);
    ph[a] = 0; pl[a] = 0;
}

// =================== split-bf16 MFMA GEMM, 128x128 tile, BK=32 ===================
// Counted-vmcnt 2-deep pipeline; per-wave 64x64 output.
// SWZ=1 (conv only): balanced 2D XCD chunk, grid must be (8,64).
// PRIO=1 (conv only): s_setprio around the MFMA cluster.
enum { A_SPLIT=0, A_CONV=1, A_GATHER2=2 };
enum { EP_RANK=0, EP_DUAL=1, EP_FINAL=2 };

#define SBSZ(Pv) ((((Pv)==3)?16384:8192) + 8192*(((Pv)>=2)?2:1))

template<int AM, int EP, int PASSES, int SWZ, int PRIO>
__global__ __launch_bounds__(256, ((2*SBSZ(PASSES)) <= 32768) ? 4 : (((2*SBSZ(PASSES)) <= 49152) ? 3 : 2))
void mgemm(const void* __restrict__ A1, const void* __restrict__ A2,
           const u16* __restrict__ Bh, const u16* __restrict__ Bl,
           float* __restrict__ Ca, float* __restrict__ Cb,
           int N, int Kd, int ldb,
           const int4* __restrict__ sched, const int* __restrict__ stok,
           const float* __restrict__ sw, const float* __restrict__ bias)
{
    constexpr bool HAL = (PASSES==3);
    constexpr bool HBL = (PASSES>=2);
    constexpr int OAL  = 8192;
    constexpr int OBH  = (HAL ? 16384 : 8192);
    constexpr int OBL  = OBH + 8192;
    constexpr int SB   = OBH + 8192*(HBL ? 2 : 1);
    constexpr int NLOADS = 2*(HBL ? 2 : 1) + 2*(HAL ? 2 : 1);
    __shared__ uint4 ldsv[2*SB/16];
    char* lds = (char*)ldsv;

    const int tid  = threadIdx.x;
    const int lane = tid & 63, wid = tid >> 6;
    int n0 = blockIdx.x * 128;

    int slot0 = 0, m0 = 0, koff = 0, kz = 0;
    const u16 *bhb = Bh, *blb = Bl;
    if (AM == A_GATHER2) {
        int4 sc = sched[blockIdx.y];
        if (!sc.z) return;
        slot0 = sc.x;
        size_t wo = (size_t)sc.y * N * ldb;
        bhb = Bh + wo; blb = Bl + wo;
    } else if (AM == A_CONV) {
        if (SWZ == 1) {
            int fid = blockIdx.y * 8 + blockIdx.x;
            int xcd = fid & 7, k = fid >> 3;
            int mp = (xcd >> 1) * 8 + (k >> 3);          // 0..31
            int np = (xcd & 1) * 8 + (k & 7);            // 0..15
            m0 = mp * 128;
            kz = np >> 3;
            koff = kz * Kd;
            n0 = (np & 7) * 128;
        } else {
            m0 = (blockIdx.y & 31) * 128;
            kz = blockIdx.y >> 5;
            koff = kz * Kd;
        }
    } else {
        m0 = blockIdx.y * 128;
    }

    // staging geometry
    int srow[2], klog[2];
    #pragma unroll
    for (int c = 0; c < 2; c++) {
        int row = (tid >> 2) + c*64;
        srow[c] = row;
        klog[c] = ((tid & 3) ^ ((row >> 1) & 3)) << 3;
    }

    const u16 *bgh[2], *bgl[2];
    #pragma unroll
    for (int c = 0; c < 2; c++) {
        size_t off = (size_t)(n0 + srow[c]) * ldb + koff + klog[c];
        bgh[c] = bhb + off;
        bgl[c] = blb + off;
    }

    const u16 *a1p[2], *a2p[2];
    #pragma unroll
    for (int c = 0; c < 2; c++) {
        if (AM == A_SPLIT) {
            size_t off = (size_t)(m0 + srow[c]) * Kd + klog[c];
            a1p[c] = (const u16*)A1 + off;
            a2p[c] = (const u16*)A2 + off;
        } else if (AM == A_CONV) {
            int t = m0 + srow[c];
            size_t rb = (((size_t)(t >> 11)*SP_ + (t & (S_-1))) << 10) + koff + klog[c];
            a1p[c] = (const u16*)A1 + rb;
            a2p[c] = (const u16*)A2 + rb;
        } else { // A_GATHER2
            int s = stok[slot0 + srow[c]];
            int tk = (s < 0) ? 0 : (s & 4095);
            size_t off = (size_t)tk * Kd + klog[c];
            a1p[c] = (const u16*)A1 + off;
            a2p[c] = (const u16*)A2 + off;
        }
    }

    // fragment read offsets (swizzle matches staging); 4 waves as 2x2 of 64x64
    const int wr = wid >> 1, wc = wid & 1;
    const int l15 = lane & 15, kq = lane >> 4;
    int aoff[4], boff[4];
    #pragma unroll
    for (int m = 0; m < 4; m++) {
        int ra = wr*64 + m*16 + l15;
        aoff[m] = ra*64 + ((kq ^ ((ra >> 1) & 3)) << 4);
    }
    #pragma unroll
    for (int n = 0; n < 4; n++) {
        int rb = wc*64 + n*16 + l15;
        boff[n] = rb*64 + ((kq ^ ((rb >> 1) & 3)) << 4);
    }

    f32x4 acc[4][4];
    #pragma unroll
    for (int m = 0; m < 4; m++)
        #pragma unroll
        for (int n = 0; n < 4; n++) acc[m][n] = {0.f,0.f,0.f,0.f};

    const int nt = Kd >> 5;

#define STAGE_GL(K0, BB)                                                          \
    {                                                                             \
        _Pragma("unroll")                                                         \
        for (int c = 0; c < 2; c++) {                                             \
            GLDS16(bgh[c] + (K0), lds + (BB) + OBH + c*4096 + (wid<<10));         \
            if (HBL)                                                              \
                GLDS16(bgl[c] + (K0), lds + (BB) + OBL + c*4096 + (wid<<10));     \
        }                                                                         \
        _Pragma("unroll")                                                         \
        for (int c = 0; c < 2; c++) {                                             \
            GLDS16(a1p[c] + (K0), lds + (BB) + c*4096 + (wid<<10));               \
            if (HAL)                                                              \
                GLDS16(a2p[c] + (K0), lds + (BB) + OAL + c*4096 + (wid<<10));     \
        }                                                                         \
    }

    // prologue: 2-deep prefetch
    STAGE_GL(0, 0);
    STAGE_GL(32, SB);
    waitvm<NLOADS>();
    __builtin_amdgcn_s_barrier();

    for (int it = 0; it < nt; ++it) {
        const int bb = (it & 1) * SB;
        {
            bf16x8 ah[4], al[4], bhf[4], blf[4];
            #pragma unroll
            for (int m = 0; m < 4; m++) {
                ah[m] = *(const bf16x8*)(lds + bb + aoff[m]);
                if (HAL) al[m] = *(const bf16x8*)(lds + bb + OAL + aoff[m]);
            }
            #pragma unroll
            for (int n = 0; n < 4; n++) {
                bhf[n] = *(const bf16x8*)(lds + bb + OBH + boff[n]);
                if (HBL) blf[n] = *(const bf16x8*)(lds + bb + OBL + boff[n]);
            }
            if (PRIO) __builtin_amdgcn_s_setprio(1);
            #pragma unroll
            for (int m = 0; m < 4; m++)
                #pragma unroll
                for (int n = 0; n < 4; n++) {
                    acc[m][n] = __builtin_amdgcn_mfma_f32_16x16x32_bf16(ah[m], bhf[n], acc[m][n], 0, 0, 0);
                    if (HAL)
                        acc[m][n] = __builtin_amdgcn_mfma_f32_16x16x32_bf16(al[m], bhf[n], acc[m][n], 0, 0, 0);
                    if (HBL)
                        acc[m][n] = __builtin_amdgcn_mfma_f32_16x16x32_bf16(ah[m], blf[n], acc[m][n], 0, 0, 0);
                }
            if (PRIO) __builtin_amdgcn_s_setprio(0);
        }
        asm volatile("s_waitcnt lgkmcnt(0)" ::: "memory");
        __builtin_amdgcn_sched_barrier(0);
        __builtin_amdgcn_s_barrier();
        if (it + 2 < nt) {
            STAGE_GL((it + 2) << 5, bb);
            waitvm<NLOADS>();
            __builtin_amdgcn_s_barrier();
        } else if (it + 1 < nt) {
            waitvm<0>();
            __builtin_amdgcn_s_barrier();
        }
    }

    // epilogue: C/D layout col=lane&15, row=(lane>>4)*4+reg
    #pragma unroll
    for (int m = 0; m < 4; m++) {
        #pragma unroll
        for (int n = 0; n < 4; n++) {
            f32x4 v = acc[m][n];
            int rl0 = wr*64 + m*16 + (lane >> 4)*4;
            int col = n0 + wc*64 + n*16 + l15;
            #pragma unroll
            for (int j = 0; j < 4; j++) {
                float x = v[j];
                int rl = rl0 + j;
                if (EP == EP_RANK) {
                    int s = stok[slot0 + rl];
                    if (s >= 0) {
                        int tt = s & 4095;
                        float ww = sw[slot0 + rl];
                        float* dst = (s & 4096) ? Cb : Ca;
                        dst[(size_t)tt * N + col] = ww * x;
                    }
                } else if (EP == EP_DUAL) {
                    int r = m0 + rl;
                    float* dst = kz ? Cb : Ca;
                    dst[(size_t)r * N + col] = x;
                } else { // EP_FINAL
                    int r = m0 + rl;
                    x += bias[r];
                    int b = col >> 11, s = col & (S_-1);
                    Ca[(((size_t)(b*CLASSES_ + r)) << 11) + s] = x;
                }
            }
        }
    }
#undef STAGE_GL
}

// ---------------- chunked cumsum over Oa+Ob ----------------
#define SC_ 128
#define NCH_ (S_/SC_)
__global__ void cum1(const float* __restrict__ Oa, const float* __restrict__ Ob,
                     float* __restrict__ CS)
{
    int blk = blockIdx.x;
    int b = blk / NCH_, ch = blk % NCH_;
    int c = threadIdx.x;
    int s0 = ch * SC_;
    size_t base = ((size_t)(b*S_ + s0)) * (3*F_) + c;
    float sum = 0.f;
    for (int s = 0; s < SC_; s++) {
        size_t idx = base + (size_t)s * (3*F_);
        sum += Oa[idx] + Ob[idx];
    }
    CS[(size_t)blk * F_ + c] = sum;
}
__global__ void cum23(const float* __restrict__ Oa, const float* __restrict__ Ob,
                      const float* __restrict__ CS, float* __restrict__ FP)
{
    int blk = blockIdx.x;
    int b = blk / NCH_, ch = blk % NCH_;
    int c = threadIdx.x;
    float run = 0.f;
    for (int j = 0; j < ch; j++) run += CS[(size_t)(b*NCH_ + j) * F_ + c];
    int s0 = ch * SC_;
    for (int s = s0; s < s0 + SC_; s++) {
        size_t t = (size_t)b * S_ + s;
        size_t ro = t * (3*F_);
        run += Oa[ro + c] + Ob[ro + c];
        float scl = Oa[ro + F_ + c] + Ob[ro + F_ + c];
        float shf = Oa[ro + 2*F_ + c] + Ob[ro + 2*F_ + c];
        FP[t*F_ + c] = run / (float)(s + 1) * scl + shf;
    }
}

// ---- fused norm + recurrence; X1 kept as bf16 hi/lo; Xcat-hi on last layer; slot reset ----
__global__ __launch_bounds__(256) void normupd_k(const float* __restrict__ FP,
                                                 float* __restrict__ X0,
                                                 u16* __restrict__ X1h, u16* __restrict__ X1l,
                                                 u16* __restrict__ xch,
                                                 int* __restrict__ stok, int* __restrict__ cnt)
{
    __shared__ float sb[4];
    int t = blockIdx.x;
    const float* row = FP + (size_t)t * F_;
    int tid = threadIdx.x;
    float v0 = row[tid], v1 = row[tid + 256];
    float s = v0 + v1;
    #pragma unroll
    for (int off = 32; off; off >>= 1) s += __shfl_xor(s, off);
    int w = tid >> 6;
    if ((tid & 63) == 0) sb[w] = s;
    __syncthreads();
    float mean = (sb[0] + sb[1] + sb[2] + sb[3]) * (1.0f / F_);
    v0 -= mean; v1 -= mean;
    float q = v0*v0 + v1*v1;
    #pragma unroll
    for (int off = 32; off; off >>= 1) q += __shfl_xor(q, off);
    __syncthreads();
    if ((tid & 63) == 0) sb[w] = q;
    __syncthreads();
    float ss = sb[0] + sb[1] + sb[2] + sb[3];
    float denom = sqrtf(ss) * 0.04419417382415922f + 1e-5f;
    float sc = 0.70710678118654752f / denom;
    float f0 = v0 * sc, f1 = v1 * sc;
    size_t i0 = (size_t)t * F_ + tid, i1 = i0 + 256;
    float a0 = 0.9f * X0[i0] + 0.1f * f0;
    float a1 = 0.9f * X0[i1] + 0.1f * f1;
    float x1o0 = b2f(X1h[i0]) + b2f(X1l[i0]);
    float x1o1 = b2f(X1h[i1]) + b2f(X1l[i1]);
    float x1n0 = x1o0 + a0;
    float x1n1 = x1o1 + a1;
    X0[i0] = a0; X0[i1] = a1;
    u16 h, l;
    fsplit(x1n0, h, l); X1h[i0] = h; X1l[i0] = l;
    fsplit(x1n1, h, l); X1h[i1] = h; X1l[i1] = l;
    if (xch) {   // last layer: write Xcat-hi = [X0_new | X1_new] in bf16
        size_t xb = (size_t)t * (2*F_);
        xch[xb + tid]            = f2b(a0);
        xch[xb + tid + 256]      = f2b(a1);
        xch[xb + F_ + tid]       = f2b(x1n0);
        xch[xb + F_ + tid + 256] = f2b(x1n1);
    }
    int gi = blockIdx.x * 256 + tid;
    if (gi < NSLOT_) stok[gi] = -1;
    if (gi < E_) cnt[gi] = 0;
}

extern "C" void kernel_launch(void* const* d_in, const int* in_sizes, int n_in,
                              void* d_out, int out_size, void* d_ws, size_t ws_size,
                              hipStream_t stream)
{
    const int*   inp    = (const int*)  d_in[0];
    const float* embed  = (const float*)d_in[1];
    const float* gin_w  = (const float*)d_in[2];
    const float* w_in   = (const float*)d_in[3];
    const float* conv_w = (const float*)d_in[4];
    const float* gout_w = (const float*)d_in[5];
    const float* w_out  = (const float*)d_in[6];
    const float* out_w  = (const float*)d_in[7];
    const float* out_b  = (const float*)d_in[8];
    float* out = (float*)d_out;

    char* w = (char*)d_ws;
    auto alloc = [&](size_t bytes) { char* r = w; w += (bytes + 255) & ~(size_t)255; return r; };
    float* X0    = (float*)alloc((size_t)T_*F_*4);
    u16*   X1h   = (u16*)  alloc((size_t)T_*F_*2);
    u16*   X1l   = (u16*)  alloc((size_t)T_*F_*2);
    u16*   Hpadh = (u16*)  alloc((size_t)B_*SP_*I_*2);
    u16*   Hpadl = (u16*)  alloc((size_t)B_*SP_*I_*2);
    u16*   HCh   = (u16*)  alloc((size_t)T_*I_*2);
    u16*   HCl   = (u16*)  alloc((size_t)T_*I_*2);
    float* FP    = (float*)alloc((size_t)T_*F_*4);
    float* CS    = (float*)alloc((size_t)B_*NCH_*F_*4);
    char*  ar1   = alloc((size_t)T_*3*F_*4);                // Ha / Oa / Xcat-hi
    char*  ar2   = alloc((size_t)T_*I_*4);                  // HC0 / OutWh
    char*  altr  = alloc((size_t)T_*3*F_*4);                // Hb / HC1 / Ob
    u16*   Wh    = (u16*)  alloc((size_t)I_*KW_*I_*2);
    u16*   Wl    = (u16*)  alloc((size_t)I_*KW_*I_*2);
    int2*  e2    = (int2*) alloc((size_t)T_*8);
    float2* w2   = (float2*)alloc((size_t)T_*8);
    int*   stok  = (int*)  alloc((size_t)NSLOT_*4);
    float* sw    = (float*)alloc((size_t)NSLOT_*4);
    int*   cnt   = (int*)  alloc(64);
    int4*  s0    = (int4*) alloc((size_t)GMAX_*16);
    int4*  s1    = (int4*) alloc((size_t)GMAX_*16);

    float* Ha  = (float*)ar1;
    float* Oa  = (float*)ar1;
    float* HC0 = (float*)ar2;
    float* Hb  = (float*)altr;
    float* HC1 = (float*)altr;
    float* Ob  = (float*)altr;
    u16*   Xch = (u16*)ar1;                // last-layer Xcat-hi (written by normupd)
    u16*   OWh = (u16*)ar2;

    embed_k<<<T_, 256, 0, stream>>>(inp, embed, X0, X1h, X1l, stok, cnt);
    hpadzero_k<<<(B_*6*I_)/256, 256, 0, stream>>>(Hpadh, Hpadl);

    for (int d = 0; d < D_; ++d) {
        // ---------- MoE1 (sparse gather from persistent bf16 X1, rank-split stores) ----------
        gatebf_k<<<T_/8, 512, 0, stream>>>(X1h, X1l, gin_w + (size_t)d*F_*E_, e2, w2, cnt);
        schedscat_k<<<1, 256, 0, stream>>>(cnt, e2, w2, s0, s1, 8, stok, sw);
        transp_k<<<dim3(I_/32, F_/32, E_), 256, 0, stream>>>(
            w_in + (size_t)d*E_*F_*I_, Wh, Wl, F_, I_);
        mgemm<A_GATHER2, EP_RANK, 3, 0, 0><<<dim3(I_/128, GMAX_), 256, 0, stream>>>(
            X1h, X1l, Wh, Wl, Ha, Hb, I_, F_, F_, s0, stok, sw, nullptr);
        hsplit_k<<<T_*I_/1024, 256, 0, stream>>>(Ha, Hb, Hpadh, Hpadl, stok, cnt);

        // ---------- causal conv (dense, K-split 2, XCD-chunked, setprio) ----------
        convw_k<<<I_, 256, 0, stream>>>(conv_w + (size_t)d*I_*I_*KW_, Wh, Wl);
        mgemm<A_CONV, EP_DUAL, 3, 1, 1><<<dim3(8, 64), 256, 0, stream>>>(
            Hpadh, Hpadl, Wh, Wl, HC0, HC1, I_, (KW_*I_)/2, KW_*I_, nullptr, nullptr, nullptr, nullptr);

        // ---------- MoE2 (fused gate + crelu split, sparse gather, rank-split stores) ----------
        gatecrelu_k<<<T_/8, 512, 0, stream>>>(HC0, HC1, gout_w + (size_t)d*I_*E_,
                                              HCh, HCl, e2, w2, cnt);
        schedscat_k<<<1, 256, 0, stream>>>(cnt, e2, w2, s0, s1, 4, stok, sw);
        for (int c = 0; c < 2; ++c) {
            transp_k<<<dim3((3*F_)/32, I_/32, 4), 256, 0, stream>>>(
                w_out + (size_t)d*E_*I_*(3*F_) + (size_t)c*4*I_*(3*F_), Wh, Wl, I_, 3*F_);
            const int4* sc = (c == 0) ? s0 : s1;
            if (d == 0)
                mgemm<A_GATHER2, EP_RANK, 3, 0, 0><<<dim3((3*F_)/128, GMAX_), 256, 0, stream>>>(
                    HCh, HCl, Wh, Wl, Oa, Ob, 3*F_, I_, I_, sc, stok, sw, nullptr);
            else
                mgemm<A_GATHER2, EP_RANK, 1, 0, 0><<<dim3((3*F_)/128, GMAX_), 256, 0, stream>>>(
                    HCh, HCl, Wh, Wl, Oa, Ob, 3*F_, I_, I_, sc, stok, sw, nullptr);
        }

        cum1<<<B_*NCH_, F_, 0, stream>>>(Oa, Ob, CS);
        cum23<<<B_*NCH_, F_, 0, stream>>>(Oa, Ob, CS, FP);
        normupd_k<<<T_, 256, 0, stream>>>(FP, X0, X1h, X1l,
                                          (d == D_-1) ? Xch : (u16*)nullptr, stok, cnt);
    }

    // ---------- final vocab GEMM (1-pass: OWh.Xh) ----------
    splith_k<<<(CLASSES_*2*F_)/1024, 256, 0, stream>>>(out_w, OWh);
    mgemm<A_SPLIT, EP_FINAL, 1, 0, 0><<<dim3(T_/128, CLASSES_/128), 256, 0, stream>>>(
        OWh, OWh, Xch, Xch, out, nullptr, T_, 2*F_, 2*F_, nullptr, nullptr, nullptr, out_b);
}